// Round 1
// baseline (1201.274 us; speedup 1.0000x reference)
//
#include <hip/hip_runtime.h>
#include <math.h>

#define NN 10000
#define EE 160000
#define CSZ 128

#define INV_S8  0.35355339059327373f   // 1/sqrt(8)
#define INV_S32 0.17677669529663687f   // 1/sqrt(32)
#define INV_S2  0.7071067811865476f    // 1/sqrt(2)
#define INV_S3  0.5773502691896258f    // 1/sqrt(3)

__device__ __forceinline__ unsigned enc_f(float x){
  unsigned u = __float_as_uint(x);
  return (u & 0x80000000u) ? ~u : (u | 0x80000000u);
}
__device__ __forceinline__ float dec_f(unsigned e){
  unsigned u = (e & 0x80000000u) ? (e & 0x7fffffffu) : ~e;
  return __uint_as_float(u);
}

// ---------------- Kernel 1: f0 = frame@Wf0+b, f1raw = frame@Wf1+b ----------
// block 64 (1 wave): lane <-> output column c (0..159), 16 nodes per block.y.
// frame reads are wave-uniform -> s_load; W reads coalesced across lanes.
__global__ __launch_bounds__(64) void k_f0f1(
    const float* __restrict__ frame,
    const float* __restrict__ Wf0, const float* __restrict__ bf0,
    const float* __restrict__ Wf1, const float* __restrict__ bf1,
    float* __restrict__ f0f1){
  int c = blockIdx.x*64 + threadIdx.x;
  int n0 = blockIdx.y*16;
  if(c >= 160) return;
  bool is0 = c < 64;
  int cc = is0 ? c : (c-64);
  float acc[16];
  float b = is0 ? bf0[cc] : bf1[cc];
  #pragma unroll
  for(int j=0;j<16;j++) acc[j] = b;
  for(int k=0;k<CSZ;k++){
    float w = is0 ? Wf0[k*64+cc] : Wf1[k*96+cc];
    #pragma unroll
    for(int j=0;j<16;j++)
      acc[j] = fmaf(frame[(size_t)(n0+j)*CSZ + k], w, acc[j]);
  }
  #pragma unroll
  for(int j=0;j<16;j++) f0f1[(size_t)(n0+j)*160 + c] = acc[j];
}

// ---------------- Kernel 2: rotate f1, gs, gv, q_s, q_v --------------------
// block 256 = 4 nodes x 64 lanes.
__global__ __launch_bounds__(256) void k_node2(
    const float* __restrict__ f0f1, const float* __restrict__ rot,
    const float* __restrict__ trans, const float* __restrict__ tfn,
    const float* __restrict__ Wgs, const float* __restrict__ Wgv,
    const float* __restrict__ Wqs, const float* __restrict__ Wqv,
    float* __restrict__ Gs, float* __restrict__ Gv,
    float* __restrict__ Qs, float* __restrict__ Qv){
  __shared__ float f1r[4][32][3];
  int ln = threadIdx.x & 63;
  int g  = threadIdx.x >> 6;
  int n  = blockIdx.x*4 + g;
  if(n < NN && ln < 32){
    int u = ln;
    float v0 = f0f1[(size_t)n*160 + 64 + u*3 + 0];
    float v1 = f0f1[(size_t)n*160 + 64 + u*3 + 1];
    float v2 = f0f1[(size_t)n*160 + 64 + u*3 + 2];
    const float* R = rot + (size_t)n*9;
    const float* t = trans + (size_t)n*3;
    f1r[g][u][0] = R[0]*v0 + R[1]*v1 + R[2]*v2 + t[0];
    f1r[g][u][1] = R[3]*v0 + R[4]*v1 + R[5]*v2 + t[1];
    f1r[g][u][2] = R[6]*v0 + R[7]*v1 + R[8]*v2 + t[2];
  }
  __syncthreads();
  if(n >= NN) return;
  if(ln < 16){
    int w = ln; float a = 0.f;
    for(int u=0;u<64;u++) a = fmaf(f0f1[(size_t)n*160+u], Wgs[u*16+w], a);
    Gs[(size_t)n*16+w] = a * 0.125f;               // /sqrt(64)
  } else if(ln < 40){
    int idx = ln-16, w = idx/3, i = idx%3; float a = 0.f;
    for(int u=0;u<32;u++) a = fmaf(f1r[g][u][i], Wgv[u*8+w], a);
    Gv[(size_t)n*24+idx] = a * INV_S32;            // /sqrt(32)
  }
  if(ln < 16){
    int w = ln; float a = 0.f;
    for(int u=0;u<16;u++) a = fmaf(tfn[(size_t)n*40+u], Wqs[u*16+w], a);
    Qs[(size_t)n*16+w] = a * 0.25f;                // /sqrt(16)
  } else if(ln < 40){
    int idx = ln-16, w = idx/3, i = idx%3; float a = 0.f;
    for(int u=0;u<8;u++) a = fmaf(tfn[(size_t)n*40+16+u*3+i], Wqv[u*8+w], a);
    Qv[(size_t)n*24+idx] = a * INV_S8;             // /sqrt(8)
  }
}

// ---------------- Kernel 3: edge K path -> attn logits + segment max -------
// thread-per-edge; TP input features in per-thread LDS columns (dynamic u idx),
// hidden[32] in regs (h fully unrolled), weights are wave-uniform s_loads.
__global__ __launch_bounds__(256) void k_edge_k(
    const int* __restrict__ ei, const float* __restrict__ esh,
    const float* __restrict__ ef,
    const float* __restrict__ Gs, const float* __restrict__ Gv,
    const float* __restrict__ Qs, const float* __restrict__ Qv,
    const float* __restrict__ Wk1, const float* __restrict__ bk1,
    const float* __restrict__ Wk2, const float* __restrict__ bk2,
    float* __restrict__ Attn, unsigned* __restrict__ Menc){
  __shared__ float lds[48*256];   // rows: 0..15 c=fs/4, 16..23 b=dv/sqrt8, 24..47 fv
  int tid = threadIdx.x;
  int e = blockIdx.x*256 + tid;
  int dst = ei[e], src = ei[EE + e];
  float4 sh4 = *(const float4*)(esh + (size_t)e*4);
  float shs = sh4.x, sv0 = sh4.y, sv1 = sh4.z, sv2 = sh4.w;
  {
    const float4* gsp = (const float4*)(Gs + (size_t)dst*16);
    #pragma unroll
    for(int q=0;q<4;q++){
      float4 t = gsp[q];
      lds[(q*4+0)*256+tid] = t.x*0.25f; lds[(q*4+1)*256+tid] = t.y*0.25f;
      lds[(q*4+2)*256+tid] = t.z*0.25f; lds[(q*4+3)*256+tid] = t.w*0.25f;
    }
    float fv[24];
    const float4* gvp = (const float4*)(Gv + (size_t)dst*24);
    #pragma unroll
    for(int q=0;q<6;q++){
      float4 t = gvp[q];
      fv[q*4+0]=t.x; fv[q*4+1]=t.y; fv[q*4+2]=t.z; fv[q*4+3]=t.w;
    }
    #pragma unroll
    for(int u=0;u<8;u++){
      lds[(16+u)*256+tid] = (fv[u*3]*sv0 + fv[u*3+1]*sv1 + fv[u*3+2]*sv2) * INV_S8;
      lds[(24+u*3+0)*256+tid] = fv[u*3+0];
      lds[(24+u*3+1)*256+tid] = fv[u*3+1];
      lds[(24+u*3+2)*256+tid] = fv[u*3+2];
    }
  }
  float hid[32];
  {
    float efv[32];
    const float4* efp = (const float4*)(ef + (size_t)e*32);
    #pragma unroll
    for(int q=0;q<8;q++){ float4 t=efp[q]; efv[q*4]=t.x; efv[q*4+1]=t.y; efv[q*4+2]=t.z; efv[q*4+3]=t.w; }
    #pragma unroll
    for(int h=0;h<32;h++) hid[h] = bk1[h];
    #pragma unroll
    for(int k=0;k<32;k++){
      float ekv = efv[k];
      #pragma unroll
      for(int h=0;h<32;h++) hid[h] = fmaf(ekv, Wk1[k*32+h], hid[h]);
    }
    #pragma unroll
    for(int h=0;h<32;h++) hid[h] = fmaxf(hid[h], 0.f);
  }
  float ks[16];
  #pragma unroll
  for(int w=0;w<16;w++) ks[w]=0.f;
  // path A (0e*0e): base 0, u<16
  for(int u=0;u<16;u++){
    float au = lds[u*256+tid] * shs;
    float kw[16];
    #pragma unroll
    for(int w=0;w<16;w++) kw[w] = bk2[u*16+w];
    #pragma unroll
    for(int h=0;h<32;h++){
      float hh = hid[h];
      const float* Wr = Wk2 + h*640 + u*16;
      #pragma unroll
      for(int w=0;w<16;w++) kw[w] = fmaf(hh, Wr[w], kw[w]);
    }
    #pragma unroll
    for(int w=0;w<16;w++) ks[w] = fmaf(au, kw[w], ks[w]);
  }
  // path B (1o.1o dot): base 256, u<8
  for(int u=0;u<8;u++){
    float bu = lds[(16+u)*256+tid];
    float kw[16];
    #pragma unroll
    for(int w=0;w<16;w++) kw[w] = bk2[256+u*16+w];
    #pragma unroll
    for(int h=0;h<32;h++){
      float hh = hid[h];
      const float* Wr = Wk2 + h*640 + 256 + u*16;
      #pragma unroll
      for(int w=0;w<16;w++) kw[w] = fmaf(hh, Wr[w], kw[w]);
    }
    #pragma unroll
    for(int w=0;w<16;w++) ks[w] = fmaf(bu, kw[w], ks[w]);
  }
  float kv[24];
  #pragma unroll
  for(int j=0;j<24;j++) kv[j]=0.f;
  // path C (0e*1o): base 384, O1=8
  for(int u=0;u<16;u++){
    float cu = lds[u*256+tid];
    float kw[8];
    #pragma unroll
    for(int w=0;w<8;w++) kw[w] = bk2[384+u*8+w];
    #pragma unroll
    for(int h=0;h<32;h++){
      float hh = hid[h];
      const float* Wr = Wk2 + h*640 + 384 + u*8;
      #pragma unroll
      for(int w=0;w<8;w++) kw[w] = fmaf(hh, Wr[w], kw[w]);
    }
    #pragma unroll
    for(int w=0;w<8;w++){
      float t = cu*kw[w];
      kv[w*3+0] = fmaf(t, sv0, kv[w*3+0]);
      kv[w*3+1] = fmaf(t, sv1, kv[w*3+1]);
      kv[w*3+2] = fmaf(t, sv2, kv[w*3+2]);
    }
  }
  // path D (1o*0e): base 512
  for(int u=0;u<8;u++){
    float s = shs * INV_S8;
    float d0 = lds[(24+u*3+0)*256+tid]*s;
    float d1 = lds[(24+u*3+1)*256+tid]*s;
    float d2 = lds[(24+u*3+2)*256+tid]*s;
    float kw[8];
    #pragma unroll
    for(int w=0;w<8;w++) kw[w] = bk2[512+u*8+w];
    #pragma unroll
    for(int h=0;h<32;h++){
      float hh = hid[h];
      const float* Wr = Wk2 + h*640 + 512 + u*8;
      #pragma unroll
      for(int w=0;w<8;w++) kw[w] = fmaf(hh, Wr[w], kw[w]);
    }
    #pragma unroll
    for(int w=0;w<8;w++){
      kv[w*3+0] = fmaf(d0, kw[w], kv[w*3+0]);
      kv[w*3+1] = fmaf(d1, kw[w], kv[w*3+1]);
      kv[w*3+2] = fmaf(d2, kw[w], kv[w*3+2]);
    }
  }
  // path E (1o x 1o cross): base 576
  for(int u=0;u<8;u++){
    float a0 = lds[(24+u*3+0)*256+tid];
    float a1 = lds[(24+u*3+1)*256+tid];
    float a2 = lds[(24+u*3+2)*256+tid];
    float x0 = (a1*sv2 - a2*sv1)*INV_S8;
    float x1 = (a2*sv0 - a0*sv2)*INV_S8;
    float x2 = (a0*sv1 - a1*sv0)*INV_S8;
    float kw[8];
    #pragma unroll
    for(int w=0;w<8;w++) kw[w] = bk2[576+u*8+w];
    #pragma unroll
    for(int h=0;h<32;h++){
      float hh = hid[h];
      const float* Wr = Wk2 + h*640 + 576 + u*8;
      #pragma unroll
      for(int w=0;w<8;w++) kw[w] = fmaf(hh, Wr[w], kw[w]);
    }
    #pragma unroll
    for(int w=0;w<8;w++){
      kv[w*3+0] = fmaf(x0, kw[w], kv[w*3+0]);
      kv[w*3+1] = fmaf(x1, kw[w], kv[w*3+1]);
      kv[w*3+2] = fmaf(x2, kw[w], kv[w*3+2]);
    }
  }
  #pragma unroll
  for(int w=0;w<16;w++) ks[w] *= INV_S2;
  #pragma unroll
  for(int j=0;j<24;j++) kv[j] *= INV_S3;
  const float* qsp = Qs + (size_t)src*16;
  const float* qvp = Qv + (size_t)src*24;
  #pragma unroll
  for(int h=0;h<4;h++){
    float a = 0.f;
    #pragma unroll
    for(int j=0;j<4;j++) a = fmaf(qsp[h*4+j], ks[h*4+j], a);
    #pragma unroll
    for(int j=0;j<6;j++) a = fmaf(qvp[h*6+j], kv[h*6+j], a);
    Attn[(size_t)e*4+h] = a;
    atomicMax(&Menc[(size_t)src*4+h], enc_f(a));
  }
}

// ---------------- Kernel 4: edge V path -> exp + atomic scatter ------------
__global__ __launch_bounds__(256) void k_edge_v(
    const int* __restrict__ ei, const float* __restrict__ esh,
    const float* __restrict__ ef,
    const float* __restrict__ Gs, const float* __restrict__ Gv,
    const float* __restrict__ Wv1, const float* __restrict__ bv1,
    const float* __restrict__ Wv2, const float* __restrict__ bv2,
    const float* __restrict__ Attn, const unsigned* __restrict__ Menc,
    float* __restrict__ Den, float* __restrict__ NumS, float* __restrict__ NumV){
  __shared__ float lds[48*256];
  int tid = threadIdx.x;
  int e = blockIdx.x*256 + tid;
  int dst = ei[e], src = ei[EE + e];
  float4 sh4 = *(const float4*)(esh + (size_t)e*4);
  float shs = sh4.x, sv0 = sh4.y, sv1 = sh4.z, sv2 = sh4.w;
  {
    const float4* gsp = (const float4*)(Gs + (size_t)dst*16);
    #pragma unroll
    for(int q=0;q<4;q++){
      float4 t = gsp[q];
      lds[(q*4+0)*256+tid] = t.x*0.25f; lds[(q*4+1)*256+tid] = t.y*0.25f;
      lds[(q*4+2)*256+tid] = t.z*0.25f; lds[(q*4+3)*256+tid] = t.w*0.25f;
    }
    float fv[24];
    const float4* gvp = (const float4*)(Gv + (size_t)dst*24);
    #pragma unroll
    for(int q=0;q<6;q++){
      float4 t = gvp[q];
      fv[q*4+0]=t.x; fv[q*4+1]=t.y; fv[q*4+2]=t.z; fv[q*4+3]=t.w;
    }
    #pragma unroll
    for(int u=0;u<8;u++){
      lds[(16+u)*256+tid] = (fv[u*3]*sv0 + fv[u*3+1]*sv1 + fv[u*3+2]*sv2) * INV_S8;
      lds[(24+u*3+0)*256+tid] = fv[u*3+0];
      lds[(24+u*3+1)*256+tid] = fv[u*3+1];
      lds[(24+u*3+2)*256+tid] = fv[u*3+2];
    }
  }
  float hid[32];
  {
    float efv[32];
    const float4* efp = (const float4*)(ef + (size_t)e*32);
    #pragma unroll
    for(int q=0;q<8;q++){ float4 t=efp[q]; efv[q*4]=t.x; efv[q*4+1]=t.y; efv[q*4+2]=t.z; efv[q*4+3]=t.w; }
    #pragma unroll
    for(int h=0;h<32;h++) hid[h] = bv1[h];
    #pragma unroll
    for(int k=0;k<32;k++){
      float ekv = efv[k];
      #pragma unroll
      for(int h=0;h<32;h++) hid[h] = fmaf(ekv, Wv1[k*32+h], hid[h]);
    }
    #pragma unroll
    for(int h=0;h<32;h++) hid[h] = fmaxf(hid[h], 0.f);
  }
  float vs[16];
  #pragma unroll
  for(int w=0;w<16;w++) vs[w]=0.f;
  // path A: base 0
  for(int u=0;u<16;u++){
    float au = lds[u*256+tid] * shs;
    float kw[16];
    #pragma unroll
    for(int w=0;w<16;w++) kw[w] = bv2[u*16+w];
    #pragma unroll
    for(int h=0;h<32;h++){
      float hh = hid[h];
      const float* Wr = Wv2 + h*896 + u*16;
      #pragma unroll
      for(int w=0;w<16;w++) kw[w] = fmaf(hh, Wr[w], kw[w]);
    }
    #pragma unroll
    for(int w=0;w<16;w++) vs[w] = fmaf(au, kw[w], vs[w]);
  }
  // path B: base 256
  for(int u=0;u<8;u++){
    float bu = lds[(16+u)*256+tid];
    float kw[16];
    #pragma unroll
    for(int w=0;w<16;w++) kw[w] = bv2[256+u*16+w];
    #pragma unroll
    for(int h=0;h<32;h++){
      float hh = hid[h];
      const float* Wr = Wv2 + h*896 + 256 + u*16;
      #pragma unroll
      for(int w=0;w<16;w++) kw[w] = fmaf(hh, Wr[w], kw[w]);
    }
    #pragma unroll
    for(int w=0;w<16;w++) vs[w] = fmaf(bu, kw[w], vs[w]);
  }
  float vv[48];
  #pragma unroll
  for(int j=0;j<48;j++) vv[j]=0.f;
  // path C: base 384, O1=16
  for(int u=0;u<16;u++){
    float cu = lds[u*256+tid];
    float kw[16];
    #pragma unroll
    for(int w=0;w<16;w++) kw[w] = bv2[384+u*16+w];
    #pragma unroll
    for(int h=0;h<32;h++){
      float hh = hid[h];
      const float* Wr = Wv2 + h*896 + 384 + u*16;
      #pragma unroll
      for(int w=0;w<16;w++) kw[w] = fmaf(hh, Wr[w], kw[w]);
    }
    #pragma unroll
    for(int w=0;w<16;w++){
      float t = cu*kw[w];
      vv[w*3+0] = fmaf(t, sv0, vv[w*3+0]);
      vv[w*3+1] = fmaf(t, sv1, vv[w*3+1]);
      vv[w*3+2] = fmaf(t, sv2, vv[w*3+2]);
    }
  }
  // path D: base 640
  for(int u=0;u<8;u++){
    float s = shs * INV_S8;
    float d0 = lds[(24+u*3+0)*256+tid]*s;
    float d1 = lds[(24+u*3+1)*256+tid]*s;
    float d2 = lds[(24+u*3+2)*256+tid]*s;
    float kw[16];
    #pragma unroll
    for(int w=0;w<16;w++) kw[w] = bv2[640+u*16+w];
    #pragma unroll
    for(int h=0;h<32;h++){
      float hh = hid[h];
      const float* Wr = Wv2 + h*896 + 640 + u*16;
      #pragma unroll
      for(int w=0;w<16;w++) kw[w] = fmaf(hh, Wr[w], kw[w]);
    }
    #pragma unroll
    for(int w=0;w<16;w++){
      vv[w*3+0] = fmaf(d0, kw[w], vv[w*3+0]);
      vv[w*3+1] = fmaf(d1, kw[w], vv[w*3+1]);
      vv[w*3+2] = fmaf(d2, kw[w], vv[w*3+2]);
    }
  }
  // path E: base 768
  for(int u=0;u<8;u++){
    float a0 = lds[(24+u*3+0)*256+tid];
    float a1 = lds[(24+u*3+1)*256+tid];
    float a2 = lds[(24+u*3+2)*256+tid];
    float x0 = (a1*sv2 - a2*sv1)*INV_S8;
    float x1 = (a2*sv0 - a0*sv2)*INV_S8;
    float x2 = (a0*sv1 - a1*sv0)*INV_S8;
    float kw[16];
    #pragma unroll
    for(int w=0;w<16;w++) kw[w] = bv2[768+u*16+w];
    #pragma unroll
    for(int h=0;h<32;h++){
      float hh = hid[h];
      const float* Wr = Wv2 + h*896 + 768 + u*16;
      #pragma unroll
      for(int w=0;w<16;w++) kw[w] = fmaf(hh, Wr[w], kw[w]);
    }
    #pragma unroll
    for(int w=0;w<16;w++){
      vv[w*3+0] = fmaf(x0, kw[w], vv[w*3+0]);
      vv[w*3+1] = fmaf(x1, kw[w], vv[w*3+1]);
      vv[w*3+2] = fmaf(x2, kw[w], vv[w*3+2]);
    }
  }
  #pragma unroll
  for(int w=0;w<16;w++) vs[w] *= INV_S2;
  #pragma unroll
  for(int j=0;j<48;j++) vv[j] *= INV_S3;
  float ex[4];
  #pragma unroll
  for(int h=0;h<4;h++){
    float m = dec_f(Menc[(size_t)src*4+h]);
    float a = Attn[(size_t)e*4+h];
    ex[h] = __expf(a - m);
    atomicAdd(&Den[(size_t)src*4+h], ex[h]);
  }
  #pragma unroll
  for(int w=0;w<16;w++){
    float t = ex[w>>2];
    atomicAdd(&NumS[(size_t)src*16+w], t*vs[w]);
    atomicAdd(&NumV[(size_t)src*48+w*3+0], t*vv[w*3+0]);
    atomicAdd(&NumV[(size_t)src*48+w*3+1], t*vv[w*3+1]);
    atomicAdd(&NumV[(size_t)src*48+w*3+2], t*vv[w*3+2]);
  }
}

// ---------------- Kernel 5: node output GEMMs + BN stats -------------------
__global__ __launch_bounds__(256) void k_nodeout(
    const float* __restrict__ NumS, const float* __restrict__ NumV,
    const float* __restrict__ Den, const float* __restrict__ tfn,
    const float* __restrict__ Wos, const float* __restrict__ Wov,
    const float* __restrict__ Wss, const float* __restrict__ Wsv,
    float* __restrict__ Pre, float* __restrict__ Stats){
  int n = blockIdx.x*256 + threadIdx.x;
  int lane = threadIdx.x & 63;
  float os[16], ov[24];
  if(n < NN){
    float rd[4];
    #pragma unroll
    for(int h=0;h<4;h++) rd[h] = 1.f/(Den[(size_t)n*4+h] + 1e-9f);
    float us[16];
    #pragma unroll
    for(int u=0;u<16;u++) us[u] = NumS[(size_t)n*16+u] * rd[u>>2];
    float uv[48];
    #pragma unroll
    for(int u=0;u<16;u++){
      float r = rd[u>>2];
      uv[u*3+0] = NumV[(size_t)n*48+u*3+0]*r;
      uv[u*3+1] = NumV[(size_t)n*48+u*3+1]*r;
      uv[u*3+2] = NumV[(size_t)n*48+u*3+2]*r;
    }
    float ts[16];
    #pragma unroll
    for(int u=0;u<16;u++) ts[u] = tfn[(size_t)n*40+u];
    #pragma unroll
    for(int w=0;w<16;w++){
      float a=0.f, b=0.f;
      #pragma unroll
      for(int u=0;u<16;u++){ a = fmaf(us[u], Wos[u*16+w], a); b = fmaf(ts[u], Wss[u*16+w], b); }
      os[w] = (a + b)*0.25f;
    }
    float tv[24];
    #pragma unroll
    for(int j=0;j<24;j++) tv[j] = tfn[(size_t)n*40+16+j];
    #pragma unroll
    for(int w=0;w<8;w++){
      #pragma unroll
      for(int i=0;i<3;i++){
        float a=0.f;
        #pragma unroll
        for(int u=0;u<16;u++) a = fmaf(uv[u*3+i], Wov[u*8+w], a);
        float b=0.f;
        #pragma unroll
        for(int u=0;u<8;u++) b = fmaf(tv[u*3+i], Wsv[u*8+w], b);
        ov[w*3+i] = a*0.25f + b*INV_S8;
      }
    }
    float* p = Pre + (size_t)n*40;
    #pragma unroll
    for(int w=0;w<16;w++) p[w] = os[w];
    #pragma unroll
    for(int j=0;j<24;j++) p[16+j] = ov[j];
  } else {
    #pragma unroll
    for(int w=0;w<16;w++) os[w]=0.f;
    #pragma unroll
    for(int j=0;j<24;j++) ov[j]=0.f;
  }
#define WAVE_RED_ADD(v) { v += __shfl_xor(v,1); v += __shfl_xor(v,2); v += __shfl_xor(v,4); \
                          v += __shfl_xor(v,8); v += __shfl_xor(v,16); v += __shfl_xor(v,32); }
  #pragma unroll
  for(int c=0;c<16;c++){
    float s = os[c];       WAVE_RED_ADD(s);
    float q = os[c]*os[c]; WAVE_RED_ADD(q);
    if(lane==0){ atomicAdd(&Stats[c], s); atomicAdd(&Stats[16+c], q); }
  }
  #pragma unroll
  for(int w=0;w<8;w++){
    float q = ov[w*3]*ov[w*3] + ov[w*3+1]*ov[w*3+1] + ov[w*3+2]*ov[w*3+2];
    WAVE_RED_ADD(q);
    if(lane==0) atomicAdd(&Stats[32+w], q);
  }
#undef WAVE_RED_ADD
}

// ---------------- Kernel 6: finalize BN + write output ---------------------
__global__ __launch_bounds__(256) void k_final(
    const float* __restrict__ Pre, const float* __restrict__ Stats,
    const float* __restrict__ bnws, const float* __restrict__ bnbs,
    const float* __restrict__ bnwv, float* __restrict__ Out){
  int idx = blockIdx.x*256 + threadIdx.x;
  if(idx >= NN*40) return;
  int n = idx/40, c = idx - n*40;
  float x = Pre[idx];
  float r;
  if(c < 16){
    float mu  = Stats[c]    * (1.f/NN);
    float var = Stats[16+c] * (1.f/NN) - mu*mu;
    r = (x - mu) / sqrtf(var + 1e-5f) * bnws[c] + bnbs[c];
  } else {
    int w = (c-16)/3;
    float n2 = Stats[32+w] * (1.f/NN);
    r = x / sqrtf(n2 + 1e-5f) * bnwv[w];
  }
  Out[idx] = r;
}

extern "C" void kernel_launch(void* const* d_in, const int* in_sizes, int n_in,
                              void* d_out, int out_size, void* d_ws, size_t ws_size,
                              hipStream_t stream){
  const float* frame = (const float*)d_in[0];
  const float* rot   = (const float*)d_in[1];
  const float* trans = (const float*)d_in[2];
  const float* tfn   = (const float*)d_in[3];
  const float* ef    = (const float*)d_in[4];
  const float* esh   = (const float*)d_in[5];
  const int*   ei    = (const int*)  d_in[6];
  const float* Wf0   = (const float*)d_in[7];
  const float* bf0   = (const float*)d_in[8];
  const float* Wf1   = (const float*)d_in[9];
  const float* bf1   = (const float*)d_in[10];
  const float* Wgs   = (const float*)d_in[11];
  const float* Wgv   = (const float*)d_in[12];
  const float* Wqs   = (const float*)d_in[13];
  const float* Wqv   = (const float*)d_in[14];
  const float* Wk1   = (const float*)d_in[15];
  const float* bk1   = (const float*)d_in[16];
  const float* Wk2   = (const float*)d_in[17];
  const float* bk2   = (const float*)d_in[18];
  const float* Wv1   = (const float*)d_in[19];
  const float* bv1   = (const float*)d_in[20];
  const float* Wv2   = (const float*)d_in[21];
  const float* bv2   = (const float*)d_in[22];
  const float* Wos   = (const float*)d_in[23];
  const float* Wov   = (const float*)d_in[24];
  const float* Wss   = (const float*)d_in[25];
  const float* Wsv   = (const float*)d_in[26];
  const float* bnws  = (const float*)d_in[27];
  const float* bnbs  = (const float*)d_in[28];
  const float* bnwv  = (const float*)d_in[29];

  float* ws   = (float*)d_ws;
  float* f0f1 = ws;                                  // N*160
  float* Gs   = f0f1 + (size_t)NN*160;               // N*16
  float* Gv   = Gs   + (size_t)NN*16;                // N*24
  float* Qs   = Gv   + (size_t)NN*24;                // N*16
  float* Qv   = Qs   + (size_t)NN*16;                // N*24
  float* Attn = Qv   + (size_t)NN*24;                // E*4
  float* Pre  = Attn + (size_t)EE*4;                 // N*40
  unsigned* Menc = (unsigned*)(Pre + (size_t)NN*40); // N*4
  float* Den  = (float*)(Menc + (size_t)NN*4);       // N*4
  float* NumS = Den  + (size_t)NN*4;                 // N*16
  float* NumV = NumS + (size_t)NN*16;                // N*48
  float* Stats= NumV + (size_t)NN*48;                // 40 (+pad)

  // zero the atomically-accumulated region each launch (ws not re-poisoned)
  size_t zero_bytes = ((size_t)NN*(4+4+16+48) + 64) * sizeof(float);
  hipMemsetAsync(Menc, 0, zero_bytes, stream);

  k_f0f1 <<<dim3(3, NN/16),        64,  0, stream>>>(frame, Wf0, bf0, Wf1, bf1, f0f1);
  k_node2<<<dim3(NN/4),            256, 0, stream>>>(f0f1, rot, trans, tfn, Wgs, Wgv, Wqs, Wqv, Gs, Gv, Qs, Qv);
  k_edge_k<<<dim3(EE/256),         256, 0, stream>>>(ei, esh, ef, Gs, Gv, Qs, Qv, Wk1, bk1, Wk2, bk2, Attn, Menc);
  k_edge_v<<<dim3(EE/256),         256, 0, stream>>>(ei, esh, ef, Gs, Gv, Wv1, bv1, Wv2, bv2, Attn, Menc, Den, NumS, NumV);
  k_nodeout<<<dim3((NN+255)/256),  256, 0, stream>>>(NumS, NumV, Den, tfn, Wos, Wov, Wss, Wsv, Pre, Stats);
  k_final<<<dim3((NN*40+255)/256), 256, 0, stream>>>(Pre, Stats, bnws, bnbs, bnwv, (float*)d_out);
}

// Round 2
// 771.177 us; speedup vs baseline: 1.5577x; 1.5577x over previous
//
#include <hip/hip_runtime.h>
#include <math.h>

#define NN 10000
#define EE 160000
#define CSZ 128

#define INV_S8  0.35355339059327373f   // 1/sqrt(8)
#define INV_S32 0.17677669529663687f   // 1/sqrt(32)
#define INV_S2  0.7071067811865476f    // 1/sqrt(2)
#define INV_S3  0.5773502691896258f    // 1/sqrt(3)

// ---------------- Kernel 1: f0 = frame@Wf0+b, f1raw = frame@Wf1+b ----------
__global__ __launch_bounds__(64) void k_f0f1(
    const float* __restrict__ frame,
    const float* __restrict__ Wf0, const float* __restrict__ bf0,
    const float* __restrict__ Wf1, const float* __restrict__ bf1,
    float* __restrict__ f0f1){
  int c = blockIdx.x*64 + threadIdx.x;
  int n0 = blockIdx.y*16;
  if(c >= 160) return;
  bool is0 = c < 64;
  int cc = is0 ? c : (c-64);
  float acc[16];
  float b = is0 ? bf0[cc] : bf1[cc];
  #pragma unroll
  for(int j=0;j<16;j++) acc[j] = b;
  for(int k=0;k<CSZ;k++){
    float w = is0 ? Wf0[k*64+cc] : Wf1[k*96+cc];
    #pragma unroll
    for(int j=0;j<16;j++)
      acc[j] = fmaf(frame[(size_t)(n0+j)*CSZ + k], w, acc[j]);
  }
  #pragma unroll
  for(int j=0;j<16;j++) f0f1[(size_t)(n0+j)*160 + c] = acc[j];
}

// ---------------- Kernel 2: rotate f1, gs, gv, q_s, q_v --------------------
__global__ __launch_bounds__(256) void k_node2(
    const float* __restrict__ f0f1, const float* __restrict__ rot,
    const float* __restrict__ trans, const float* __restrict__ tfn,
    const float* __restrict__ Wgs, const float* __restrict__ Wgv,
    const float* __restrict__ Wqs, const float* __restrict__ Wqv,
    float* __restrict__ Gs, float* __restrict__ Gv,
    float* __restrict__ Qs, float* __restrict__ Qv){
  __shared__ float f1r[4][32][3];
  int ln = threadIdx.x & 63;
  int g  = threadIdx.x >> 6;
  int n  = blockIdx.x*4 + g;
  if(n < NN && ln < 32){
    int u = ln;
    float v0 = f0f1[(size_t)n*160 + 64 + u*3 + 0];
    float v1 = f0f1[(size_t)n*160 + 64 + u*3 + 1];
    float v2 = f0f1[(size_t)n*160 + 64 + u*3 + 2];
    const float* R = rot + (size_t)n*9;
    const float* t = trans + (size_t)n*3;
    f1r[g][u][0] = R[0]*v0 + R[1]*v1 + R[2]*v2 + t[0];
    f1r[g][u][1] = R[3]*v0 + R[4]*v1 + R[5]*v2 + t[1];
    f1r[g][u][2] = R[6]*v0 + R[7]*v1 + R[8]*v2 + t[2];
  }
  __syncthreads();
  if(n >= NN) return;
  if(ln < 16){
    int w = ln; float a = 0.f;
    for(int u=0;u<64;u++) a = fmaf(f0f1[(size_t)n*160+u], Wgs[u*16+w], a);
    Gs[(size_t)n*16+w] = a * 0.125f;
  } else if(ln < 40){
    int idx = ln-16, w = idx/3, i = idx%3; float a = 0.f;
    for(int u=0;u<32;u++) a = fmaf(f1r[g][u][i], Wgv[u*8+w], a);
    Gv[(size_t)n*24+idx] = a * INV_S32;
  }
  if(ln < 16){
    int w = ln; float a = 0.f;
    for(int u=0;u<16;u++) a = fmaf(tfn[(size_t)n*40+u], Wqs[u*16+w], a);
    Qs[(size_t)n*16+w] = a * 0.25f;
  } else if(ln < 40){
    int idx = ln-16, w = idx/3, i = idx%3; float a = 0.f;
    for(int u=0;u<8;u++) a = fmaf(tfn[(size_t)n*40+16+u*3+i], Wqv[u*8+w], a);
    Qv[(size_t)n*24+idx] = a * INV_S8;
  }
}

// ---------------- CSR build: histogram, scan, scatter ----------------------
__global__ __launch_bounds__(256) void k_hist(const int* __restrict__ ei, int* __restrict__ cnt){
  int e = blockIdx.x*256 + threadIdx.x;
  if(e < EE) atomicAdd(&cnt[ei[EE + e]], 1);
}

__global__ __launch_bounds__(256) void k_scan(const int* __restrict__ cnt,
                                              int* __restrict__ ofs, int* __restrict__ fill){
  __shared__ int tsum[256];
  int t = threadIdx.x;
  const int CH = (NN + 255)/256;   // 40
  int base = t*CH;
  int s = 0;
  for(int i=0;i<CH;i++){ int idx=base+i; if(idx<NN) s += cnt[idx]; }
  tsum[t] = s;
  __syncthreads();
  for(int off=1; off<256; off<<=1){
    int v = (t>=off)? tsum[t-off] : 0;
    __syncthreads();
    tsum[t] += v;
    __syncthreads();
  }
  int run = (t==0)? 0 : tsum[t-1];
  for(int i=0;i<CH;i++){
    int idx = base+i;
    if(idx < NN){ ofs[idx] = run; fill[idx] = run; run += cnt[idx]; }
  }
  if(t==255) ofs[NN] = tsum[255];
}

__global__ __launch_bounds__(256) void k_scatter(const int* __restrict__ ei,
                                                 int* __restrict__ fill, int* __restrict__ elist){
  int e = blockIdx.x*256 + threadIdx.x;
  if(e >= EE) return;
  int src = ei[EE + e];
  int pos = atomicAdd(&fill[src], 1);
  elist[pos] = e;
}

// ---------------- Kernel 3: edge K path -> attn logits (coalesced write) ---
__global__ __launch_bounds__(256) void k_edge_k(
    const int* __restrict__ ei, const float* __restrict__ esh,
    const float* __restrict__ ef,
    const float* __restrict__ Gs, const float* __restrict__ Gv,
    const float* __restrict__ Qs, const float* __restrict__ Qv,
    const float* __restrict__ Wk1, const float* __restrict__ bk1,
    const float* __restrict__ Wk2, const float* __restrict__ bk2,
    float* __restrict__ Attn){
  __shared__ float lds[48*256];
  int tid = threadIdx.x;
  int e = blockIdx.x*256 + tid;
  int dst = ei[e], src = ei[EE + e];
  float4 sh4 = *(const float4*)(esh + (size_t)e*4);
  float shs = sh4.x, sv0 = sh4.y, sv1 = sh4.z, sv2 = sh4.w;
  {
    const float4* gsp = (const float4*)(Gs + (size_t)dst*16);
    #pragma unroll
    for(int q=0;q<4;q++){
      float4 t = gsp[q];
      lds[(q*4+0)*256+tid] = t.x*0.25f; lds[(q*4+1)*256+tid] = t.y*0.25f;
      lds[(q*4+2)*256+tid] = t.z*0.25f; lds[(q*4+3)*256+tid] = t.w*0.25f;
    }
    float fv[24];
    const float4* gvp = (const float4*)(Gv + (size_t)dst*24);
    #pragma unroll
    for(int q=0;q<6;q++){
      float4 t = gvp[q];
      fv[q*4+0]=t.x; fv[q*4+1]=t.y; fv[q*4+2]=t.z; fv[q*4+3]=t.w;
    }
    #pragma unroll
    for(int u=0;u<8;u++){
      lds[(16+u)*256+tid] = (fv[u*3]*sv0 + fv[u*3+1]*sv1 + fv[u*3+2]*sv2) * INV_S8;
      lds[(24+u*3+0)*256+tid] = fv[u*3+0];
      lds[(24+u*3+1)*256+tid] = fv[u*3+1];
      lds[(24+u*3+2)*256+tid] = fv[u*3+2];
    }
  }
  float hid[32];
  {
    float efv[32];
    const float4* efp = (const float4*)(ef + (size_t)e*32);
    #pragma unroll
    for(int q=0;q<8;q++){ float4 t=efp[q]; efv[q*4]=t.x; efv[q*4+1]=t.y; efv[q*4+2]=t.z; efv[q*4+3]=t.w; }
    #pragma unroll
    for(int h=0;h<32;h++) hid[h] = bk1[h];
    #pragma unroll
    for(int k=0;k<32;k++){
      float ekv = efv[k];
      #pragma unroll
      for(int h=0;h<32;h++) hid[h] = fmaf(ekv, Wk1[k*32+h], hid[h]);
    }
    #pragma unroll
    for(int h=0;h<32;h++) hid[h] = fmaxf(hid[h], 0.f);
  }
  float ks[16];
  #pragma unroll
  for(int w=0;w<16;w++) ks[w]=0.f;
  for(int u=0;u<16;u++){
    float au = lds[u*256+tid] * shs;
    float kw[16];
    #pragma unroll
    for(int w=0;w<16;w++) kw[w] = bk2[u*16+w];
    #pragma unroll
    for(int h=0;h<32;h++){
      float hh = hid[h];
      const float* Wr = Wk2 + h*640 + u*16;
      #pragma unroll
      for(int w=0;w<16;w++) kw[w] = fmaf(hh, Wr[w], kw[w]);
    }
    #pragma unroll
    for(int w=0;w<16;w++) ks[w] = fmaf(au, kw[w], ks[w]);
  }
  for(int u=0;u<8;u++){
    float bu = lds[(16+u)*256+tid];
    float kw[16];
    #pragma unroll
    for(int w=0;w<16;w++) kw[w] = bk2[256+u*16+w];
    #pragma unroll
    for(int h=0;h<32;h++){
      float hh = hid[h];
      const float* Wr = Wk2 + h*640 + 256 + u*16;
      #pragma unroll
      for(int w=0;w<16;w++) kw[w] = fmaf(hh, Wr[w], kw[w]);
    }
    #pragma unroll
    for(int w=0;w<16;w++) ks[w] = fmaf(bu, kw[w], ks[w]);
  }
  float kv[24];
  #pragma unroll
  for(int j=0;j<24;j++) kv[j]=0.f;
  for(int u=0;u<16;u++){
    float cu = lds[u*256+tid];
    float kw[8];
    #pragma unroll
    for(int w=0;w<8;w++) kw[w] = bk2[384+u*8+w];
    #pragma unroll
    for(int h=0;h<32;h++){
      float hh = hid[h];
      const float* Wr = Wk2 + h*640 + 384 + u*8;
      #pragma unroll
      for(int w=0;w<8;w++) kw[w] = fmaf(hh, Wr[w], kw[w]);
    }
    #pragma unroll
    for(int w=0;w<8;w++){
      float t = cu*kw[w];
      kv[w*3+0] = fmaf(t, sv0, kv[w*3+0]);
      kv[w*3+1] = fmaf(t, sv1, kv[w*3+1]);
      kv[w*3+2] = fmaf(t, sv2, kv[w*3+2]);
    }
  }
  for(int u=0;u<8;u++){
    float s = shs * INV_S8;
    float d0 = lds[(24+u*3+0)*256+tid]*s;
    float d1 = lds[(24+u*3+1)*256+tid]*s;
    float d2 = lds[(24+u*3+2)*256+tid]*s;
    float kw[8];
    #pragma unroll
    for(int w=0;w<8;w++) kw[w] = bk2[512+u*8+w];
    #pragma unroll
    for(int h=0;h<32;h++){
      float hh = hid[h];
      const float* Wr = Wk2 + h*640 + 512 + u*8;
      #pragma unroll
      for(int w=0;w<8;w++) kw[w] = fmaf(hh, Wr[w], kw[w]);
    }
    #pragma unroll
    for(int w=0;w<8;w++){
      kv[w*3+0] = fmaf(d0, kw[w], kv[w*3+0]);
      kv[w*3+1] = fmaf(d1, kw[w], kv[w*3+1]);
      kv[w*3+2] = fmaf(d2, kw[w], kv[w*3+2]);
    }
  }
  for(int u=0;u<8;u++){
    float a0 = lds[(24+u*3+0)*256+tid];
    float a1 = lds[(24+u*3+1)*256+tid];
    float a2 = lds[(24+u*3+2)*256+tid];
    float x0 = (a1*sv2 - a2*sv1)*INV_S8;
    float x1 = (a2*sv0 - a0*sv2)*INV_S8;
    float x2 = (a0*sv1 - a1*sv0)*INV_S8;
    float kw[8];
    #pragma unroll
    for(int w=0;w<8;w++) kw[w] = bk2[576+u*8+w];
    #pragma unroll
    for(int h=0;h<32;h++){
      float hh = hid[h];
      const float* Wr = Wk2 + h*640 + 576 + u*8;
      #pragma unroll
      for(int w=0;w<8;w++) kw[w] = fmaf(hh, Wr[w], kw[w]);
    }
    #pragma unroll
    for(int w=0;w<8;w++){
      kv[w*3+0] = fmaf(x0, kw[w], kv[w*3+0]);
      kv[w*3+1] = fmaf(x1, kw[w], kv[w*3+1]);
      kv[w*3+2] = fmaf(x2, kw[w], kv[w*3+2]);
    }
  }
  #pragma unroll
  for(int w=0;w<16;w++) ks[w] *= INV_S2;
  #pragma unroll
  for(int j=0;j<24;j++) kv[j] *= INV_S3;
  const float* qsp = Qs + (size_t)src*16;
  const float* qvp = Qv + (size_t)src*24;
  float at[4];
  #pragma unroll
  for(int h=0;h<4;h++){
    float a = 0.f;
    #pragma unroll
    for(int j=0;j<4;j++) a = fmaf(qsp[h*4+j], ks[h*4+j], a);
    #pragma unroll
    for(int j=0;j<6;j++) a = fmaf(qvp[h*6+j], kv[h*6+j], a);
    at[h] = a;
  }
  *(float4*)(Attn + (size_t)e*4) = make_float4(at[0], at[1], at[2], at[3]);
}

// ---------------- Kernel 4: edge V path -> per-edge V record (coalesced) ---
__global__ __launch_bounds__(256) void k_edge_v(
    const int* __restrict__ ei, const float* __restrict__ esh,
    const float* __restrict__ ef,
    const float* __restrict__ Gs, const float* __restrict__ Gv,
    const float* __restrict__ Wv1, const float* __restrict__ bv1,
    const float* __restrict__ Wv2, const float* __restrict__ bv2,
    float* __restrict__ EdgeV){
  __shared__ float lds[48*256];
  int tid = threadIdx.x;
  int e = blockIdx.x*256 + tid;
  int dst = ei[e];
  float4 sh4 = *(const float4*)(esh + (size_t)e*4);
  float shs = sh4.x, sv0 = sh4.y, sv1 = sh4.z, sv2 = sh4.w;
  {
    const float4* gsp = (const float4*)(Gs + (size_t)dst*16);
    #pragma unroll
    for(int q=0;q<4;q++){
      float4 t = gsp[q];
      lds[(q*4+0)*256+tid] = t.x*0.25f; lds[(q*4+1)*256+tid] = t.y*0.25f;
      lds[(q*4+2)*256+tid] = t.z*0.25f; lds[(q*4+3)*256+tid] = t.w*0.25f;
    }
    float fv[24];
    const float4* gvp = (const float4*)(Gv + (size_t)dst*24);
    #pragma unroll
    for(int q=0;q<6;q++){
      float4 t = gvp[q];
      fv[q*4+0]=t.x; fv[q*4+1]=t.y; fv[q*4+2]=t.z; fv[q*4+3]=t.w;
    }
    #pragma unroll
    for(int u=0;u<8;u++){
      lds[(16+u)*256+tid] = (fv[u*3]*sv0 + fv[u*3+1]*sv1 + fv[u*3+2]*sv2) * INV_S8;
      lds[(24+u*3+0)*256+tid] = fv[u*3+0];
      lds[(24+u*3+1)*256+tid] = fv[u*3+1];
      lds[(24+u*3+2)*256+tid] = fv[u*3+2];
    }
  }
  float hid[32];
  {
    float efv[32];
    const float4* efp = (const float4*)(ef + (size_t)e*32);
    #pragma unroll
    for(int q=0;q<8;q++){ float4 t=efp[q]; efv[q*4]=t.x; efv[q*4+1]=t.y; efv[q*4+2]=t.z; efv[q*4+3]=t.w; }
    #pragma unroll
    for(int h=0;h<32;h++) hid[h] = bv1[h];
    #pragma unroll
    for(int k=0;k<32;k++){
      float ekv = efv[k];
      #pragma unroll
      for(int h=0;h<32;h++) hid[h] = fmaf(ekv, Wv1[k*32+h], hid[h]);
    }
    #pragma unroll
    for(int h=0;h<32;h++) hid[h] = fmaxf(hid[h], 0.f);
  }
  float vs[16];
  #pragma unroll
  for(int w=0;w<16;w++) vs[w]=0.f;
  for(int u=0;u<16;u++){
    float au = lds[u*256+tid] * shs;
    float kw[16];
    #pragma unroll
    for(int w=0;w<16;w++) kw[w] = bv2[u*16+w];
    #pragma unroll
    for(int h=0;h<32;h++){
      float hh = hid[h];
      const float* Wr = Wv2 + h*896 + u*16;
      #pragma unroll
      for(int w=0;w<16;w++) kw[w] = fmaf(hh, Wr[w], kw[w]);
    }
    #pragma unroll
    for(int w=0;w<16;w++) vs[w] = fmaf(au, kw[w], vs[w]);
  }
  for(int u=0;u<8;u++){
    float bu = lds[(16+u)*256+tid];
    float kw[16];
    #pragma unroll
    for(int w=0;w<16;w++) kw[w] = bv2[256+u*16+w];
    #pragma unroll
    for(int h=0;h<32;h++){
      float hh = hid[h];
      const float* Wr = Wv2 + h*896 + 256 + u*16;
      #pragma unroll
      for(int w=0;w<16;w++) kw[w] = fmaf(hh, Wr[w], kw[w]);
    }
    #pragma unroll
    for(int w=0;w<16;w++) vs[w] = fmaf(bu, kw[w], vs[w]);
  }
  float vv[48];
  #pragma unroll
  for(int j=0;j<48;j++) vv[j]=0.f;
  for(int u=0;u<16;u++){
    float cu = lds[u*256+tid];
    float kw[16];
    #pragma unroll
    for(int w=0;w<16;w++) kw[w] = bv2[384+u*16+w];
    #pragma unroll
    for(int h=0;h<32;h++){
      float hh = hid[h];
      const float* Wr = Wv2 + h*896 + 384 + u*16;
      #pragma unroll
      for(int w=0;w<16;w++) kw[w] = fmaf(hh, Wr[w], kw[w]);
    }
    #pragma unroll
    for(int w=0;w<16;w++){
      float t = cu*kw[w];
      vv[w*3+0] = fmaf(t, sv0, vv[w*3+0]);
      vv[w*3+1] = fmaf(t, sv1, vv[w*3+1]);
      vv[w*3+2] = fmaf(t, sv2, vv[w*3+2]);
    }
  }
  for(int u=0;u<8;u++){
    float s = shs * INV_S8;
    float d0 = lds[(24+u*3+0)*256+tid]*s;
    float d1 = lds[(24+u*3+1)*256+tid]*s;
    float d2 = lds[(24+u*3+2)*256+tid]*s;
    float kw[16];
    #pragma unroll
    for(int w=0;w<16;w++) kw[w] = bv2[640+u*16+w];
    #pragma unroll
    for(int h=0;h<32;h++){
      float hh = hid[h];
      const float* Wr = Wv2 + h*896 + 640 + u*16;
      #pragma unroll
      for(int w=0;w<16;w++) kw[w] = fmaf(hh, Wr[w], kw[w]);
    }
    #pragma unroll
    for(int w=0;w<16;w++){
      vv[w*3+0] = fmaf(d0, kw[w], vv[w*3+0]);
      vv[w*3+1] = fmaf(d1, kw[w], vv[w*3+1]);
      vv[w*3+2] = fmaf(d2, kw[w], vv[w*3+2]);
    }
  }
  for(int u=0;u<8;u++){
    float a0 = lds[(24+u*3+0)*256+tid];
    float a1 = lds[(24+u*3+1)*256+tid];
    float a2 = lds[(24+u*3+2)*256+tid];
    float x0 = (a1*sv2 - a2*sv1)*INV_S8;
    float x1 = (a2*sv0 - a0*sv2)*INV_S8;
    float x2 = (a0*sv1 - a1*sv0)*INV_S8;
    float kw[16];
    #pragma unroll
    for(int w=0;w<16;w++) kw[w] = bv2[768+u*16+w];
    #pragma unroll
    for(int h=0;h<32;h++){
      float hh = hid[h];
      const float* Wr = Wv2 + h*896 + 768 + u*16;
      #pragma unroll
      for(int w=0;w<16;w++) kw[w] = fmaf(hh, Wr[w], kw[w]);
    }
    #pragma unroll
    for(int w=0;w<16;w++){
      vv[w*3+0] = fmaf(x0, kw[w], vv[w*3+0]);
      vv[w*3+1] = fmaf(x1, kw[w], vv[w*3+1]);
      vv[w*3+2] = fmaf(x2, kw[w], vv[w*3+2]);
    }
  }
  float* out = EdgeV + (size_t)e*64;
  #pragma unroll
  for(int q=0;q<4;q++)
    ((float4*)out)[q] = make_float4(vs[q*4]*INV_S2, vs[q*4+1]*INV_S2,
                                    vs[q*4+2]*INV_S2, vs[q*4+3]*INV_S2);
  #pragma unroll
  for(int q=0;q<12;q++)
    ((float4*)out)[4+q] = make_float4(vv[q*4]*INV_S3, vv[q*4+1]*INV_S3,
                                      vv[q*4+2]*INV_S3, vv[q*4+3]*INV_S3);
}

// ---------------- Kernel 5: per-node softmax + weighted sum (no atomics) ---
// one wave per node; lane = output component c (0..15 scalar, 16..63 vector).
__global__ __launch_bounds__(256) void k_reduce(
    const int* __restrict__ ofs, const int* __restrict__ elist,
    const float* __restrict__ Attn, const float* __restrict__ EdgeV,
    float* __restrict__ Upd){
  int wid = threadIdx.x >> 6, ln = threadIdx.x & 63;
  int n = blockIdx.x*4 + wid;
  if(n >= NN) return;
  int beg = ofs[n], end = ofs[n+1];
  // pass 1: segment max per head
  float m0=-3.4e38f, m1=-3.4e38f, m2=-3.4e38f, m3=-3.4e38f;
  for(int i=beg+ln; i<end; i+=64){
    int e = elist[i];
    float4 a = *(const float4*)(Attn + (size_t)e*4);
    m0=fmaxf(m0,a.x); m1=fmaxf(m1,a.y); m2=fmaxf(m2,a.z); m3=fmaxf(m3,a.w);
  }
  #pragma unroll
  for(int off=1; off<64; off<<=1){
    m0=fmaxf(m0,__shfl_xor(m0,off)); m1=fmaxf(m1,__shfl_xor(m1,off));
    m2=fmaxf(m2,__shfl_xor(m2,off)); m3=fmaxf(m3,__shfl_xor(m3,off));
  }
  int h = (ln < 16) ? (ln >> 2) : (((ln - 16)/3) >> 2);
  float mh = (h==0)?m0:(h==1)?m1:(h==2)?m2:m3;
  // pass 2: every lane accumulates its numerator AND its head's denominator
  float acc = 0.f, den = 0.f;
  for(int i=beg; i<end; i++){
    int e = elist[i];
    float v  = EdgeV[(size_t)e*64 + ln];
    float a  = Attn[(size_t)e*4 + h];
    float ex = __expf(a - mh);
    acc = fmaf(ex, v, acc);
    den += ex;
  }
  Upd[(size_t)n*64 + ln] = acc / (den + 1e-9f);
}

// ---------------- Kernel 6: node output GEMMs + BN stats -------------------
__global__ __launch_bounds__(256) void k_nodeout(
    const float* __restrict__ Upd, const float* __restrict__ tfn,
    const float* __restrict__ Wos, const float* __restrict__ Wov,
    const float* __restrict__ Wss, const float* __restrict__ Wsv,
    float* __restrict__ Pre, float* __restrict__ Stats){
  int n = blockIdx.x*256 + threadIdx.x;
  int lane = threadIdx.x & 63;
  float os[16], ov[24];
  if(n < NN){
    float us[16];
    #pragma unroll
    for(int u=0;u<16;u++) us[u] = Upd[(size_t)n*64+u];
    float uv[48];
    #pragma unroll
    for(int j=0;j<48;j++) uv[j] = Upd[(size_t)n*64+16+j];
    float ts[16];
    #pragma unroll
    for(int u=0;u<16;u++) ts[u] = tfn[(size_t)n*40+u];
    #pragma unroll
    for(int w=0;w<16;w++){
      float a=0.f, b=0.f;
      #pragma unroll
      for(int u=0;u<16;u++){ a = fmaf(us[u], Wos[u*16+w], a); b = fmaf(ts[u], Wss[u*16+w], b); }
      os[w] = (a + b)*0.25f;
    }
    float tv[24];
    #pragma unroll
    for(int j=0;j<24;j++) tv[j] = tfn[(size_t)n*40+16+j];
    #pragma unroll
    for(int w=0;w<8;w++){
      #pragma unroll
      for(int i=0;i<3;i++){
        float a=0.f;
        #pragma unroll
        for(int u=0;u<16;u++) a = fmaf(uv[u*3+i], Wov[u*8+w], a);
        float b=0.f;
        #pragma unroll
        for(int u=0;u<8;u++) b = fmaf(tv[u*3+i], Wsv[u*8+w], b);
        ov[w*3+i] = a*0.25f + b*INV_S8;
      }
    }
    float* p = Pre + (size_t)n*40;
    #pragma unroll
    for(int w=0;w<16;w++) p[w] = os[w];
    #pragma unroll
    for(int j=0;j<24;j++) p[16+j] = ov[j];
  } else {
    #pragma unroll
    for(int w=0;w<16;w++) os[w]=0.f;
    #pragma unroll
    for(int j=0;j<24;j++) ov[j]=0.f;
  }
#define WAVE_RED_ADD(v) { v += __shfl_xor(v,1); v += __shfl_xor(v,2); v += __shfl_xor(v,4); \
                          v += __shfl_xor(v,8); v += __shfl_xor(v,16); v += __shfl_xor(v,32); }
  #pragma unroll
  for(int c=0;c<16;c++){
    float s = os[c];       WAVE_RED_ADD(s);
    float q = os[c]*os[c]; WAVE_RED_ADD(q);
    if(lane==0){ atomicAdd(&Stats[c], s); atomicAdd(&Stats[16+c], q); }
  }
  #pragma unroll
  for(int w=0;w<8;w++){
    float q = ov[w*3]*ov[w*3] + ov[w*3+1]*ov[w*3+1] + ov[w*3+2]*ov[w*3+2];
    WAVE_RED_ADD(q);
    if(lane==0) atomicAdd(&Stats[32+w], q);
  }
#undef WAVE_RED_ADD
}

// ---------------- Kernel 7: finalize BN + write output ---------------------
__global__ __launch_bounds__(256) void k_final(
    const float* __restrict__ Pre, const float* __restrict__ Stats,
    const float* __restrict__ bnws, const float* __restrict__ bnbs,
    const float* __restrict__ bnwv, float* __restrict__ Out){
  int idx = blockIdx.x*256 + threadIdx.x;
  if(idx >= NN*40) return;
  int n = idx/40, c = idx - n*40;
  float x = Pre[idx];
  float r;
  if(c < 16){
    float mu  = Stats[c]    * (1.f/NN);
    float var = Stats[16+c] * (1.f/NN) - mu*mu;
    r = (x - mu) / sqrtf(var + 1e-5f) * bnws[c] + bnbs[c];
  } else {
    int w = (c-16)/3;
    float n2 = Stats[32+w] * (1.f/NN);
    r = x / sqrtf(n2 + 1e-5f) * bnwv[w];
  }
  Out[idx] = r;
}

extern "C" void kernel_launch(void* const* d_in, const int* in_sizes, int n_in,
                              void* d_out, int out_size, void* d_ws, size_t ws_size,
                              hipStream_t stream){
  const float* frame = (const float*)d_in[0];
  const float* rot   = (const float*)d_in[1];
  const float* trans = (const float*)d_in[2];
  const float* tfn   = (const float*)d_in[3];
  const float* ef    = (const float*)d_in[4];
  const float* esh   = (const float*)d_in[5];
  const int*   ei    = (const int*)  d_in[6];
  const float* Wf0   = (const float*)d_in[7];
  const float* bf0   = (const float*)d_in[8];
  const float* Wf1   = (const float*)d_in[9];
  const float* bf1   = (const float*)d_in[10];
  const float* Wgs   = (const float*)d_in[11];
  const float* Wgv   = (const float*)d_in[12];
  const float* Wqs   = (const float*)d_in[13];
  const float* Wqv   = (const float*)d_in[14];
  const float* Wk1   = (const float*)d_in[15];
  const float* bk1   = (const float*)d_in[16];
  const float* Wk2   = (const float*)d_in[17];
  const float* bk2   = (const float*)d_in[18];
  const float* Wv1   = (const float*)d_in[19];
  const float* bv1   = (const float*)d_in[20];
  const float* Wv2   = (const float*)d_in[21];
  const float* bv2   = (const float*)d_in[22];
  const float* Wos   = (const float*)d_in[23];
  const float* Wov   = (const float*)d_in[24];
  const float* Wss   = (const float*)d_in[25];
  const float* Wsv   = (const float*)d_in[26];
  const float* bnws  = (const float*)d_in[27];
  const float* bnbs  = (const float*)d_in[28];
  const float* bnwv  = (const float*)d_in[29];

  float* ws   = (float*)d_ws;
  float* f0f1 = ws;                                   // N*160
  float* Gs   = f0f1 + (size_t)NN*160;                // N*16
  float* Gv   = Gs   + (size_t)NN*16;                 // N*24
  float* Qs   = Gv   + (size_t)NN*24;                 // N*16
  float* Qv   = Qs   + (size_t)NN*16;                 // N*24
  float* Attn = Qv   + (size_t)NN*24;                 // E*4
  float* Pre  = Attn + (size_t)EE*4;                  // N*40
  float* Upd  = Pre  + (size_t)NN*40;                 // N*64
  float* EdgeV= Upd  + (size_t)NN*64;                 // E*64
  float* Stats= EdgeV+ (size_t)EE*64;                 // 64 floats (zeroed)
  int*   cnt  = (int*)(Stats + 64);                   // N+16   (zeroed)
  int*   ofs  = cnt + (NN+16);                        // N+1
  int*   fill = ofs + (NN+1);                         // N
  int*   elist= fill + NN;                            // E

  // zero only the accumulated buffers (Stats + cnt); ws is NOT re-poisoned
  hipMemsetAsync(Stats, 0, (64 + NN + 16)*sizeof(int), stream);

  k_f0f1   <<<dim3(3, NN/16),        64,  0, stream>>>(frame, Wf0, bf0, Wf1, bf1, f0f1);
  k_node2  <<<dim3(NN/4),            256, 0, stream>>>(f0f1, rot, trans, tfn, Wgs, Wgv, Wqs, Wqv, Gs, Gv, Qs, Qv);
  k_hist   <<<dim3((EE+255)/256),    256, 0, stream>>>(ei, cnt);
  k_scan   <<<dim3(1),               256, 0, stream>>>(cnt, ofs, fill);
  k_scatter<<<dim3((EE+255)/256),    256, 0, stream>>>(ei, fill, elist);
  k_edge_k <<<dim3(EE/256),          256, 0, stream>>>(ei, esh, ef, Gs, Gv, Qs, Qv, Wk1, bk1, Wk2, bk2, Attn);
  k_edge_v <<<dim3(EE/256),          256, 0, stream>>>(ei, esh, ef, Gs, Gv, Wv1, bv1, Wv2, bv2, EdgeV);
  k_reduce <<<dim3((NN+3)/4),        256, 0, stream>>>(ofs, elist, Attn, EdgeV, Upd);
  k_nodeout<<<dim3((NN+255)/256),    256, 0, stream>>>(Upd, tfn, Wos, Wov, Wss, Wsv, Pre, Stats);
  k_final  <<<dim3((NN*40+255)/256), 256, 0, stream>>>(Pre, Stats, bnws, bnbs, bnwv, (float*)d_out);
}

// Round 3
// 703.609 us; speedup vs baseline: 1.7073x; 1.0960x over previous
//
#include <hip/hip_runtime.h>
#include <math.h>

#define NN 10000
#define EE 160000
#define CSZ 128

#define INV_S8  0.35355339059327373f   // 1/sqrt(8)
#define INV_S32 0.17677669529663687f   // 1/sqrt(32)
#define INV_S2  0.7071067811865476f    // 1/sqrt(2)
#define INV_S3  0.5773502691896258f    // 1/sqrt(3)

// ---------------- Kernel 1: f0 = frame@Wf0+b, f1raw = frame@Wf1+b ----------
__global__ __launch_bounds__(64) void k_f0f1(
    const float* __restrict__ frame,
    const float* __restrict__ Wf0, const float* __restrict__ bf0,
    const float* __restrict__ Wf1, const float* __restrict__ bf1,
    float* __restrict__ f0f1){
  int c = blockIdx.x*64 + threadIdx.x;
  int n0 = blockIdx.y*16;
  if(c >= 160) return;
  bool is0 = c < 64;
  int cc = is0 ? c : (c-64);
  float acc[16];
  float b = is0 ? bf0[cc] : bf1[cc];
  #pragma unroll
  for(int j=0;j<16;j++) acc[j] = b;
  for(int k=0;k<CSZ;k++){
    float w = is0 ? Wf0[k*64+cc] : Wf1[k*96+cc];
    #pragma unroll
    for(int j=0;j<16;j++)
      acc[j] = fmaf(frame[(size_t)(n0+j)*CSZ + k], w, acc[j]);
  }
  #pragma unroll
  for(int j=0;j<16;j++) f0f1[(size_t)(n0+j)*160 + c] = acc[j];
}

// ---------------- Kernel 2: rotate f1, gs, gv, q_s, q_v --------------------
__global__ __launch_bounds__(256) void k_node2(
    const float* __restrict__ f0f1, const float* __restrict__ rot,
    const float* __restrict__ trans, const float* __restrict__ tfn,
    const float* __restrict__ Wgs, const float* __restrict__ Wgv,
    const float* __restrict__ Wqs, const float* __restrict__ Wqv,
    float* __restrict__ Gs, float* __restrict__ Gv,
    float* __restrict__ Qs, float* __restrict__ Qv){
  __shared__ float f1r[4][32][3];
  int ln = threadIdx.x & 63;
  int g  = threadIdx.x >> 6;
  int n  = blockIdx.x*4 + g;
  if(n < NN && ln < 32){
    int u = ln;
    float v0 = f0f1[(size_t)n*160 + 64 + u*3 + 0];
    float v1 = f0f1[(size_t)n*160 + 64 + u*3 + 1];
    float v2 = f0f1[(size_t)n*160 + 64 + u*3 + 2];
    const float* R = rot + (size_t)n*9;
    const float* t = trans + (size_t)n*3;
    f1r[g][u][0] = R[0]*v0 + R[1]*v1 + R[2]*v2 + t[0];
    f1r[g][u][1] = R[3]*v0 + R[4]*v1 + R[5]*v2 + t[1];
    f1r[g][u][2] = R[6]*v0 + R[7]*v1 + R[8]*v2 + t[2];
  }
  __syncthreads();
  if(n >= NN) return;
  if(ln < 16){
    int w = ln; float a = 0.f;
    for(int u=0;u<64;u++) a = fmaf(f0f1[(size_t)n*160+u], Wgs[u*16+w], a);
    Gs[(size_t)n*16+w] = a * 0.125f;
  } else if(ln < 40){
    int idx = ln-16, w = idx/3, i = idx%3; float a = 0.f;
    for(int u=0;u<32;u++) a = fmaf(f1r[g][u][i], Wgv[u*8+w], a);
    Gv[(size_t)n*24+idx] = a * INV_S32;
  }
  if(ln < 16){
    int w = ln; float a = 0.f;
    for(int u=0;u<16;u++) a = fmaf(tfn[(size_t)n*40+u], Wqs[u*16+w], a);
    Qs[(size_t)n*16+w] = a * 0.25f;
  } else if(ln < 40){
    int idx = ln-16, w = idx/3, i = idx%3; float a = 0.f;
    for(int u=0;u<8;u++) a = fmaf(tfn[(size_t)n*40+16+u*3+i], Wqv[u*8+w], a);
    Qv[(size_t)n*24+idx] = a * INV_S8;
  }
}

// ---------------- CSR build ------------------------------------------------
__global__ __launch_bounds__(256) void k_hist(const int* __restrict__ ei, int* __restrict__ cnt){
  int e = blockIdx.x*256 + threadIdx.x;
  if(e < EE) atomicAdd(&cnt[ei[EE + e]], 1);
}

__global__ __launch_bounds__(256) void k_scan(const int* __restrict__ cnt,
                                              int* __restrict__ ofs, int* __restrict__ fill){
  __shared__ int tsum[256];
  int t = threadIdx.x;
  const int CH = (NN + 255)/256;   // 40
  int base = t*CH;
  int s = 0;
  for(int i=0;i<CH;i++){ int idx=base+i; if(idx<NN) s += cnt[idx]; }
  tsum[t] = s;
  __syncthreads();
  for(int off=1; off<256; off<<=1){
    int v = (t>=off)? tsum[t-off] : 0;
    __syncthreads();
    tsum[t] += v;
    __syncthreads();
  }
  int run = (t==0)? 0 : tsum[t-1];
  for(int i=0;i<CH;i++){
    int idx = base+i;
    if(idx < NN){ ofs[idx] = run; fill[idx] = run; run += cnt[idx]; }
  }
  if(t==255) ofs[NN] = tsum[255];
}

__global__ __launch_bounds__(256) void k_scatter(const int* __restrict__ ei,
                                                 int* __restrict__ fill, int* __restrict__ elist){
  int e = blockIdx.x*256 + threadIdx.x;
  if(e >= EE) return;
  int src = ei[EE + e];
  int pos = atomicAdd(&fill[src], 1);
  elist[pos] = e;
}

// ---------------- shared device helpers ------------------------------------
__device__ __forceinline__ void mlp_hidden(const float* __restrict__ ef, int e,
    const float* __restrict__ W1, const float* __restrict__ b1, float hid[32]){
  float efv[32];
  const float4* efp = (const float4*)(ef + (size_t)e*32);
  #pragma unroll
  for(int q=0;q<8;q++){ float4 t=efp[q]; efv[q*4]=t.x; efv[q*4+1]=t.y; efv[q*4+2]=t.z; efv[q*4+3]=t.w; }
  #pragma unroll
  for(int h=0;h<32;h++) hid[h] = b1[h];
  #pragma unroll
  for(int k=0;k<32;k++){
    float ekv = efv[k];
    #pragma unroll
    for(int h=0;h<32;h++) hid[h] = fmaf(ekv, W1[k*32+h], hid[h]);
  }
  #pragma unroll
  for(int h=0;h<32;h++) hid[h] = fmaxf(hid[h], 0.f);
}

// stage a 32-row x 128-col weight chunk (row stride RS) into LDS [32][128]
template<int RS>
__device__ __forceinline__ void stage_w(const float* __restrict__ W2, int cb,
                                        float* __restrict__ Wsh, int tid){
  #pragma unroll
  for(int i=0;i<4;i++){
    int f4 = i*256 + tid;        // 0..1023 float4 index
    int h  = f4 >> 5;            // 32 float4 per row
    int c4 = f4 & 31;
    *(float4*)&Wsh[h*128 + c4*4] = *(const float4*)&W2[(size_t)h*RS + cb + c4*4];
  }
}

// kw[16] = bias + hid @ Wsh[:, c0:c0+16]  (all reads are wave-uniform -> LDS broadcast)
__device__ __forceinline__ void kw16f(const float* __restrict__ Wsh,
                                      const float* __restrict__ bsh,
                                      const float hid[32], int c0, float kw[16]){
  #pragma unroll
  for(int q=0;q<4;q++){
    float4 b = *(const float4*)&bsh[c0+q*4];
    kw[q*4]=b.x; kw[q*4+1]=b.y; kw[q*4+2]=b.z; kw[q*4+3]=b.w;
  }
  #pragma unroll
  for(int h=0;h<32;h++){
    float hh = hid[h];
    const float* wr = &Wsh[h*128 + c0];
    #pragma unroll
    for(int q=0;q<4;q++){
      float4 w4 = *(const float4*)&wr[q*4];
      kw[q*4]   = fmaf(hh, w4.x, kw[q*4]);
      kw[q*4+1] = fmaf(hh, w4.y, kw[q*4+1]);
      kw[q*4+2] = fmaf(hh, w4.z, kw[q*4+2]);
      kw[q*4+3] = fmaf(hh, w4.w, kw[q*4+3]);
    }
  }
}

__device__ __forceinline__ void kw8f(const float* __restrict__ Wsh,
                                     const float* __restrict__ bsh,
                                     const float hid[32], int c0, float kw[8]){
  #pragma unroll
  for(int q=0;q<2;q++){
    float4 b = *(const float4*)&bsh[c0+q*4];
    kw[q*4]=b.x; kw[q*4+1]=b.y; kw[q*4+2]=b.z; kw[q*4+3]=b.w;
  }
  #pragma unroll
  for(int h=0;h<32;h++){
    float hh = hid[h];
    const float* wr = &Wsh[h*128 + c0];
    #pragma unroll
    for(int q=0;q<2;q++){
      float4 w4 = *(const float4*)&wr[q*4];
      kw[q*4]   = fmaf(hh, w4.x, kw[q*4]);
      kw[q*4+1] = fmaf(hh, w4.y, kw[q*4+1]);
      kw[q*4+2] = fmaf(hh, w4.z, kw[q*4+2]);
      kw[q*4+3] = fmaf(hh, w4.w, kw[q*4+3]);
    }
  }
}

// ---------------- Edge V, paths A+B (scalar outputs, cols 0..383) ----------
__global__ __launch_bounds__(256) void k_edge_v_ab(
    const int* __restrict__ ei, const float* __restrict__ esh,
    const float* __restrict__ ef,
    const float* __restrict__ Gs, const float* __restrict__ Gv,
    const float* __restrict__ W1, const float* __restrict__ b1,
    const float* __restrict__ W2, const float* __restrict__ b2,
    float* __restrict__ EdgeV){
  __shared__ float Fa[16*256];      // fs*0.25*shs
  __shared__ float Fb[8*256];       // dv*INV_S8
  __shared__ float Wsh[32*128];
  __shared__ float bsh[128];
  int tid = threadIdx.x;
  int e = blockIdx.x*256 + tid;
  int dst = ei[e];
  float4 sh4 = *(const float4*)(esh + (size_t)e*4);
  float shs=sh4.x, sv0=sh4.y, sv1=sh4.z, sv2=sh4.w;
  {
    const float4* gsp = (const float4*)(Gs + (size_t)dst*16);
    float sc = 0.25f*shs;
    #pragma unroll
    for(int q=0;q<4;q++){
      float4 t = gsp[q];
      Fa[(q*4+0)*256+tid]=t.x*sc; Fa[(q*4+1)*256+tid]=t.y*sc;
      Fa[(q*4+2)*256+tid]=t.z*sc; Fa[(q*4+3)*256+tid]=t.w*sc;
    }
    float fv[24];
    const float4* gvp = (const float4*)(Gv + (size_t)dst*24);
    #pragma unroll
    for(int q=0;q<6;q++){ float4 t=gvp[q]; fv[q*4]=t.x; fv[q*4+1]=t.y; fv[q*4+2]=t.z; fv[q*4+3]=t.w; }
    #pragma unroll
    for(int u=0;u<8;u++)
      Fb[u*256+tid] = (fv[u*3]*sv0 + fv[u*3+1]*sv1 + fv[u*3+2]*sv2) * INV_S8;
  }
  float hid[32];
  mlp_hidden(ef, e, W1, b1, hid);
  float vs[16];
  #pragma unroll
  for(int w=0;w<16;w++) vs[w]=0.f;
  for(int p=0;p<3;p++){
    __syncthreads();
    stage_w<896>(W2, p*128, Wsh, tid);
    if(tid<32) *(float4*)&bsh[tid*4] = *(const float4*)&b2[p*128+tid*4];
    __syncthreads();
    const float* F = (p<2) ? &Fa[p*8*256] : Fb;
    for(int uu=0; uu<8; uu++){
      float au = F[uu*256+tid];
      float kw[16];
      kw16f(Wsh, bsh, hid, uu*16, kw);
      #pragma unroll
      for(int w=0;w<16;w++) vs[w] = fmaf(au, kw[w], vs[w]);
    }
  }
  float* out = EdgeV + (size_t)e*64;
  #pragma unroll
  for(int q=0;q<4;q++)
    ((float4*)out)[q] = make_float4(vs[q*4]*INV_S2, vs[q*4+1]*INV_S2,
                                    vs[q*4+2]*INV_S2, vs[q*4+3]*INV_S2);
}

// ---------------- Edge V, paths C+D+E (vector outputs, cols 384..895) ------
__global__ __launch_bounds__(256) void k_edge_v_cde(
    const int* __restrict__ ei, const float* __restrict__ esh,
    const float* __restrict__ ef,
    const float* __restrict__ Gs, const float* __restrict__ Gv,
    const float* __restrict__ W1, const float* __restrict__ b1,
    const float* __restrict__ W2, const float* __restrict__ b2,
    float* __restrict__ EdgeV){
  __shared__ float Fc[16*256];      // fs*0.25
  __shared__ float Fv[24*256];      // fv
  __shared__ float Wsh[32*128];
  __shared__ float bsh[128];
  int tid = threadIdx.x;
  int e = blockIdx.x*256 + tid;
  int dst = ei[e];
  float4 sh4 = *(const float4*)(esh + (size_t)e*4);
  float shs=sh4.x, sv0=sh4.y, sv1=sh4.z, sv2=sh4.w;
  {
    const float4* gsp = (const float4*)(Gs + (size_t)dst*16);
    #pragma unroll
    for(int q=0;q<4;q++){
      float4 t = gsp[q];
      Fc[(q*4+0)*256+tid]=t.x*0.25f; Fc[(q*4+1)*256+tid]=t.y*0.25f;
      Fc[(q*4+2)*256+tid]=t.z*0.25f; Fc[(q*4+3)*256+tid]=t.w*0.25f;
    }
    const float4* gvp = (const float4*)(Gv + (size_t)dst*24);
    #pragma unroll
    for(int q=0;q<6;q++){
      float4 t = gvp[q];
      Fv[(q*4+0)*256+tid]=t.x; Fv[(q*4+1)*256+tid]=t.y;
      Fv[(q*4+2)*256+tid]=t.z; Fv[(q*4+3)*256+tid]=t.w;
    }
  }
  float hid[32];
  mlp_hidden(ef, e, W1, b1, hid);
  float vv[48];
  #pragma unroll
  for(int j=0;j<48;j++) vv[j]=0.f;
  // passes 0,1: path C (cols 384 + p*128), u = p*8..p*8+7
  for(int p=0;p<2;p++){
    __syncthreads();
    stage_w<896>(W2, 384 + p*128, Wsh, tid);
    if(tid<32) *(float4*)&bsh[tid*4] = *(const float4*)&b2[384+p*128+tid*4];
    __syncthreads();
    for(int uu=0; uu<8; uu++){
      float cu = Fc[(p*8+uu)*256+tid];
      float kw[16];
      kw16f(Wsh, bsh, hid, uu*16, kw);
      #pragma unroll
      for(int w=0;w<16;w++){
        float t = cu*kw[w];
        vv[w*3+0] = fmaf(t, sv0, vv[w*3+0]);
        vv[w*3+1] = fmaf(t, sv1, vv[w*3+1]);
        vv[w*3+2] = fmaf(t, sv2, vv[w*3+2]);
      }
    }
  }
  // pass 2: path D (cols 640..767)
  {
    __syncthreads();
    stage_w<896>(W2, 640, Wsh, tid);
    if(tid<32) *(float4*)&bsh[tid*4] = *(const float4*)&b2[640+tid*4];
    __syncthreads();
    float sD = shs * INV_S8;
    for(int uu=0; uu<8; uu++){
      float d0 = Fv[(uu*3+0)*256+tid]*sD;
      float d1 = Fv[(uu*3+1)*256+tid]*sD;
      float d2 = Fv[(uu*3+2)*256+tid]*sD;
      float kw[16];
      kw16f(Wsh, bsh, hid, uu*16, kw);
      #pragma unroll
      for(int w=0;w<16;w++){
        vv[w*3+0] = fmaf(d0, kw[w], vv[w*3+0]);
        vv[w*3+1] = fmaf(d1, kw[w], vv[w*3+1]);
        vv[w*3+2] = fmaf(d2, kw[w], vv[w*3+2]);
      }
    }
  }
  // pass 3: path E (cols 768..895)
  {
    __syncthreads();
    stage_w<896>(W2, 768, Wsh, tid);
    if(tid<32) *(float4*)&bsh[tid*4] = *(const float4*)&b2[768+tid*4];
    __syncthreads();
    for(int uu=0; uu<8; uu++){
      float a0 = Fv[(uu*3+0)*256+tid];
      float a1 = Fv[(uu*3+1)*256+tid];
      float a2 = Fv[(uu*3+2)*256+tid];
      float x0 = (a1*sv2 - a2*sv1)*INV_S8;
      float x1 = (a2*sv0 - a0*sv2)*INV_S8;
      float x2 = (a0*sv1 - a1*sv0)*INV_S8;
      float kw[16];
      kw16f(Wsh, bsh, hid, uu*16, kw);
      #pragma unroll
      for(int w=0;w<16;w++){
        vv[w*3+0] = fmaf(x0, kw[w], vv[w*3+0]);
        vv[w*3+1] = fmaf(x1, kw[w], vv[w*3+1]);
        vv[w*3+2] = fmaf(x2, kw[w], vv[w*3+2]);
      }
    }
  }
  float* out = EdgeV + (size_t)e*64 + 16;
  #pragma unroll
  for(int q=0;q<12;q++)
    ((float4*)out)[q] = make_float4(vv[q*4]*INV_S3, vv[q*4+1]*INV_S3,
                                    vv[q*4+2]*INV_S3, vv[q*4+3]*INV_S3);
}

// ---------------- Edge K, paths A+B -> partial logits ----------------------
__global__ __launch_bounds__(256) void k_edge_k_ab(
    const int* __restrict__ ei, const float* __restrict__ esh,
    const float* __restrict__ ef,
    const float* __restrict__ Gs, const float* __restrict__ Gv,
    const float* __restrict__ Qs,
    const float* __restrict__ W1, const float* __restrict__ b1,
    const float* __restrict__ W2, const float* __restrict__ b2,
    float* __restrict__ AttnP){
  __shared__ float Fa[16*256];
  __shared__ float Fb[8*256];
  __shared__ float Wsh[32*128];
  __shared__ float bsh[128];
  int tid = threadIdx.x;
  int e = blockIdx.x*256 + tid;
  int dst = ei[e], src = ei[EE + e];
  float4 sh4 = *(const float4*)(esh + (size_t)e*4);
  float shs=sh4.x, sv0=sh4.y, sv1=sh4.z, sv2=sh4.w;
  {
    const float4* gsp = (const float4*)(Gs + (size_t)dst*16);
    float sc = 0.25f*shs;
    #pragma unroll
    for(int q=0;q<4;q++){
      float4 t = gsp[q];
      Fa[(q*4+0)*256+tid]=t.x*sc; Fa[(q*4+1)*256+tid]=t.y*sc;
      Fa[(q*4+2)*256+tid]=t.z*sc; Fa[(q*4+3)*256+tid]=t.w*sc;
    }
    float fv[24];
    const float4* gvp = (const float4*)(Gv + (size_t)dst*24);
    #pragma unroll
    for(int q=0;q<6;q++){ float4 t=gvp[q]; fv[q*4]=t.x; fv[q*4+1]=t.y; fv[q*4+2]=t.z; fv[q*4+3]=t.w; }
    #pragma unroll
    for(int u=0;u<8;u++)
      Fb[u*256+tid] = (fv[u*3]*sv0 + fv[u*3+1]*sv1 + fv[u*3+2]*sv2) * INV_S8;
  }
  float hid[32];
  mlp_hidden(ef, e, W1, b1, hid);
  float ks[16];
  #pragma unroll
  for(int w=0;w<16;w++) ks[w]=0.f;
  for(int p=0;p<3;p++){
    __syncthreads();
    stage_w<640>(W2, p*128, Wsh, tid);
    if(tid<32) *(float4*)&bsh[tid*4] = *(const float4*)&b2[p*128+tid*4];
    __syncthreads();
    const float* F = (p<2) ? &Fa[p*8*256] : Fb;
    for(int uu=0; uu<8; uu++){
      float au = F[uu*256+tid];
      float kw[16];
      kw16f(Wsh, bsh, hid, uu*16, kw);
      #pragma unroll
      for(int w=0;w<16;w++) ks[w] = fmaf(au, kw[w], ks[w]);
    }
  }
  const float* qsp = Qs + (size_t)src*16;
  float at[4];
  #pragma unroll
  for(int h=0;h<4;h++){
    float a = 0.f;
    #pragma unroll
    for(int j=0;j<4;j++) a = fmaf(qsp[h*4+j], ks[h*4+j]*INV_S2, a);
    at[h] = a;
  }
  *(float4*)(AttnP + (size_t)e*4) = make_float4(at[0], at[1], at[2], at[3]);
}

// ---------------- Edge K, paths C+D+E -> final logits ----------------------
__global__ __launch_bounds__(256) void k_edge_k_cde(
    const int* __restrict__ ei, const float* __restrict__ esh,
    const float* __restrict__ ef,
    const float* __restrict__ Gs, const float* __restrict__ Gv,
    const float* __restrict__ Qv,
    const float* __restrict__ W1, const float* __restrict__ b1,
    const float* __restrict__ W2, const float* __restrict__ b2,
    const float* __restrict__ AttnP, float* __restrict__ Attn){
  __shared__ float Fc[16*256];
  __shared__ float Fv[24*256];
  __shared__ float Wsh[32*128];
  __shared__ float bsh[128];
  int tid = threadIdx.x;
  int e = blockIdx.x*256 + tid;
  int dst = ei[e], src = ei[EE + e];
  float4 sh4 = *(const float4*)(esh + (size_t)e*4);
  float shs=sh4.x, sv0=sh4.y, sv1=sh4.z, sv2=sh4.w;
  {
    const float4* gsp = (const float4*)(Gs + (size_t)dst*16);
    #pragma unroll
    for(int q=0;q<4;q++){
      float4 t = gsp[q];
      Fc[(q*4+0)*256+tid]=t.x*0.25f; Fc[(q*4+1)*256+tid]=t.y*0.25f;
      Fc[(q*4+2)*256+tid]=t.z*0.25f; Fc[(q*4+3)*256+tid]=t.w*0.25f;
    }
    const float4* gvp = (const float4*)(Gv + (size_t)dst*24);
    #pragma unroll
    for(int q=0;q<6;q++){
      float4 t = gvp[q];
      Fv[(q*4+0)*256+tid]=t.x; Fv[(q*4+1)*256+tid]=t.y;
      Fv[(q*4+2)*256+tid]=t.z; Fv[(q*4+3)*256+tid]=t.w;
    }
  }
  float hid[32];
  mlp_hidden(ef, e, W1, b1, hid);
  float kv[24];
  #pragma unroll
  for(int j=0;j<24;j++) kv[j]=0.f;
  // pass 0: path C, cols 384..511 (u0..15, w8)
  {
    __syncthreads();
    stage_w<640>(W2, 384, Wsh, tid);
    if(tid<32) *(float4*)&bsh[tid*4] = *(const float4*)&b2[384+tid*4];
    __syncthreads();
    for(int uu=0; uu<16; uu++){
      float cu = Fc[uu*256+tid];
      float kw[8];
      kw8f(Wsh, bsh, hid, uu*8, kw);
      #pragma unroll
      for(int w=0;w<8;w++){
        float t = cu*kw[w];
        kv[w*3+0] = fmaf(t, sv0, kv[w*3+0]);
        kv[w*3+1] = fmaf(t, sv1, kv[w*3+1]);
        kv[w*3+2] = fmaf(t, sv2, kv[w*3+2]);
      }
    }
  }
  // pass 1: paths D (cols 512..575) + E (cols 576..639)
  {
    __syncthreads();
    stage_w<640>(W2, 512, Wsh, tid);
    if(tid<32) *(float4*)&bsh[tid*4] = *(const float4*)&b2[512+tid*4];
    __syncthreads();
    float sD = shs * INV_S8;
    for(int uu=0; uu<8; uu++){
      float d0 = Fv[(uu*3+0)*256+tid]*sD;
      float d1 = Fv[(uu*3+1)*256+tid]*sD;
      float d2 = Fv[(uu*3+2)*256+tid]*sD;
      float kw[8];
      kw8f(Wsh, bsh, hid, uu*8, kw);
      #pragma unroll
      for(int w=0;w<8;w++){
        kv[w*3+0] = fmaf(d0, kw[w], kv[w*3+0]);
        kv[w*3+1] = fmaf(d1, kw[w], kv[w*3+1]);
        kv[w*3+2] = fmaf(d2, kw[w], kv[w*3+2]);
      }
    }
    for(int uu=0; uu<8; uu++){
      float a0 = Fv[(uu*3+0)*256+tid];
      float a1 = Fv[(uu*3+1)*256+tid];
      float a2 = Fv[(uu*3+2)*256+tid];
      float x0 = (a1*sv2 - a2*sv1)*INV_S8;
      float x1 = (a2*sv0 - a0*sv2)*INV_S8;
      float x2 = (a0*sv1 - a1*sv0)*INV_S8;
      float kw[8];
      kw8f(Wsh, bsh, hid, 64+uu*8, kw);
      #pragma unroll
      for(int w=0;w<8;w++){
        kv[w*3+0] = fmaf(x0, kw[w], kv[w*3+0]);
        kv[w*3+1] = fmaf(x1, kw[w], kv[w*3+1]);
        kv[w*3+2] = fmaf(x2, kw[w], kv[w*3+2]);
      }
    }
  }
  const float* qvp = Qv + (size_t)src*24;
  float4 ap = *(const float4*)(AttnP + (size_t)e*4);
  float at[4] = {ap.x, ap.y, ap.z, ap.w};
  #pragma unroll
  for(int h=0;h<4;h++){
    float a = at[h];
    #pragma unroll
    for(int j=0;j<6;j++) a = fmaf(qvp[h*6+j], kv[h*6+j]*INV_S3, a);
    at[h] = a;
  }
  *(float4*)(Attn + (size_t)e*4) = make_float4(at[0], at[1], at[2], at[3]);
}

// ---------------- per-node softmax + weighted sum (no atomics) -------------
__global__ __launch_bounds__(256) void k_reduce(
    const int* __restrict__ ofs, const int* __restrict__ elist,
    const float* __restrict__ Attn, const float* __restrict__ EdgeV,
    float* __restrict__ Upd){
  int wid = threadIdx.x >> 6, ln = threadIdx.x & 63;
  int n = blockIdx.x*4 + wid;
  if(n >= NN) return;
  int beg = ofs[n], end = ofs[n+1];
  float m0=-3.4e38f, m1=-3.4e38f, m2=-3.4e38f, m3=-3.4e38f;
  for(int i=beg+ln; i<end; i+=64){
    int e = elist[i];
    float4 a = *(const float4*)(Attn + (size_t)e*4);
    m0=fmaxf(m0,a.x); m1=fmaxf(m1,a.y); m2=fmaxf(m2,a.z); m3=fmaxf(m3,a.w);
  }
  #pragma unroll
  for(int off=1; off<64; off<<=1){
    m0=fmaxf(m0,__shfl_xor(m0,off)); m1=fmaxf(m1,__shfl_xor(m1,off));
    m2=fmaxf(m2,__shfl_xor(m2,off)); m3=fmaxf(m3,__shfl_xor(m3,off));
  }
  int h = (ln < 16) ? (ln >> 2) : (((ln - 16)/3) >> 2);
  float mh = (h==0)?m0:(h==1)?m1:(h==2)?m2:m3;
  float acc = 0.f, den = 0.f;
  for(int i=beg; i<end; i++){
    int e = elist[i];
    float v  = EdgeV[(size_t)e*64 + ln];
    float a  = Attn[(size_t)e*4 + h];
    float ex = __expf(a - mh);
    acc = fmaf(ex, v, acc);
    den += ex;
  }
  Upd[(size_t)n*64 + ln] = acc / (den + 1e-9f);
}

// ---------------- node output GEMMs + BN stats -----------------------------
__global__ __launch_bounds__(256) void k_nodeout(
    const float* __restrict__ Upd, const float* __restrict__ tfn,
    const float* __restrict__ Wos, const float* __restrict__ Wov,
    const float* __restrict__ Wss, const float* __restrict__ Wsv,
    float* __restrict__ Pre, float* __restrict__ Stats){
  int n = blockIdx.x*256 + threadIdx.x;
  int lane = threadIdx.x & 63;
  float os[16], ov[24];
  if(n < NN){
    float us[16];
    #pragma unroll
    for(int u=0;u<16;u++) us[u] = Upd[(size_t)n*64+u];
    float uv[48];
    #pragma unroll
    for(int j=0;j<48;j++) uv[j] = Upd[(size_t)n*64+16+j];
    float ts[16];
    #pragma unroll
    for(int u=0;u<16;u++) ts[u] = tfn[(size_t)n*40+u];
    #pragma unroll
    for(int w=0;w<16;w++){
      float a=0.f, b=0.f;
      #pragma unroll
      for(int u=0;u<16;u++){ a = fmaf(us[u], Wos[u*16+w], a); b = fmaf(ts[u], Wss[u*16+w], b); }
      os[w] = (a + b)*0.25f;
    }
    float tv[24];
    #pragma unroll
    for(int j=0;j<24;j++) tv[j] = tfn[(size_t)n*40+16+j];
    #pragma unroll
    for(int w=0;w<8;w++){
      #pragma unroll
      for(int i=0;i<3;i++){
        float a=0.f;
        #pragma unroll
        for(int u=0;u<16;u++) a = fmaf(uv[u*3+i], Wov[u*8+w], a);
        float b=0.f;
        #pragma unroll
        for(int u=0;u<8;u++) b = fmaf(tv[u*3+i], Wsv[u*8+w], b);
        ov[w*3+i] = a*0.25f + b*INV_S8;
      }
    }
    float* p = Pre + (size_t)n*40;
    #pragma unroll
    for(int w=0;w<16;w++) p[w] = os[w];
    #pragma unroll
    for(int j=0;j<24;j++) p[16+j] = ov[j];
  } else {
    #pragma unroll
    for(int w=0;w<16;w++) os[w]=0.f;
    #pragma unroll
    for(int j=0;j<24;j++) ov[j]=0.f;
  }
#define WAVE_RED_ADD(v) { v += __shfl_xor(v,1); v += __shfl_xor(v,2); v += __shfl_xor(v,4); \
                          v += __shfl_xor(v,8); v += __shfl_xor(v,16); v += __shfl_xor(v,32); }
  #pragma unroll
  for(int c=0;c<16;c++){
    float s = os[c];       WAVE_RED_ADD(s);
    float q = os[c]*os[c]; WAVE_RED_ADD(q);
    if(lane==0){ atomicAdd(&Stats[c], s); atomicAdd(&Stats[16+c], q); }
  }
  #pragma unroll
  for(int w=0;w<8;w++){
    float q = ov[w*3]*ov[w*3] + ov[w*3+1]*ov[w*3+1] + ov[w*3+2]*ov[w*3+2];
    WAVE_RED_ADD(q);
    if(lane==0) atomicAdd(&Stats[32+w], q);
  }
#undef WAVE_RED_ADD
}

// ---------------- finalize BN + write output -------------------------------
__global__ __launch_bounds__(256) void k_final(
    const float* __restrict__ Pre, const float* __restrict__ Stats,
    const float* __restrict__ bnws, const float* __restrict__ bnbs,
    const float* __restrict__ bnwv, float* __restrict__ Out){
  int idx = blockIdx.x*256 + threadIdx.x;
  if(idx >= NN*40) return;
  int n = idx/40, c = idx - n*40;
  float x = Pre[idx];
  float r;
  if(c < 16){
    float mu  = Stats[c]    * (1.f/NN);
    float var = Stats[16+c] * (1.f/NN) - mu*mu;
    r = (x - mu) / sqrtf(var + 1e-5f) * bnws[c] + bnbs[c];
  } else {
    int w = (c-16)/3;
    float n2 = Stats[32+w] * (1.f/NN);
    r = x / sqrtf(n2 + 1e-5f) * bnwv[w];
  }
  Out[idx] = r;
}

extern "C" void kernel_launch(void* const* d_in, const int* in_sizes, int n_in,
                              void* d_out, int out_size, void* d_ws, size_t ws_size,
                              hipStream_t stream){
  const float* frame = (const float*)d_in[0];
  const float* rot   = (const float*)d_in[1];
  const float* trans = (const float*)d_in[2];
  const float* tfn   = (const float*)d_in[3];
  const float* ef    = (const float*)d_in[4];
  const float* esh   = (const float*)d_in[5];
  const int*   ei    = (const int*)  d_in[6];
  const float* Wf0   = (const float*)d_in[7];
  const float* bf0   = (const float*)d_in[8];
  const float* Wf1   = (const float*)d_in[9];
  const float* bf1   = (const float*)d_in[10];
  const float* Wgs   = (const float*)d_in[11];
  const float* Wgv   = (const float*)d_in[12];
  const float* Wqs   = (const float*)d_in[13];
  const float* Wqv   = (const float*)d_in[14];
  const float* Wk1   = (const float*)d_in[15];
  const float* bk1   = (const float*)d_in[16];
  const float* Wk2   = (const float*)d_in[17];
  const float* bk2   = (const float*)d_in[18];
  const float* Wv1   = (const float*)d_in[19];
  const float* bv1   = (const float*)d_in[20];
  const float* Wv2   = (const float*)d_in[21];
  const float* bv2   = (const float*)d_in[22];
  const float* Wos   = (const float*)d_in[23];
  const float* Wov   = (const float*)d_in[24];
  const float* Wss   = (const float*)d_in[25];
  const float* Wsv   = (const float*)d_in[26];
  const float* bnws  = (const float*)d_in[27];
  const float* bnbs  = (const float*)d_in[28];
  const float* bnwv  = (const float*)d_in[29];

  float* ws   = (float*)d_ws;
  float* f0f1 = ws;                                   // N*160
  float* Gs   = f0f1 + (size_t)NN*160;                // N*16
  float* Gv   = Gs   + (size_t)NN*16;                 // N*24
  float* Qs   = Gv   + (size_t)NN*24;                 // N*16
  float* Qv   = Qs   + (size_t)NN*16;                 // N*24
  float* Attn = Qv   + (size_t)NN*24;                 // E*4
  float* Pre  = Attn + (size_t)EE*4;                  // N*40
  float* Upd  = Pre  + (size_t)NN*40;                 // N*64
  float* EdgeV= Upd  + (size_t)NN*64;                 // E*64
  float* Stats= EdgeV+ (size_t)EE*64;                 // 64 floats (zeroed)
  int*   cnt  = (int*)(Stats + 64);                   // N+16   (zeroed)
  int*   ofs  = cnt + (NN+16);                        // N+1
  int*   fill = ofs + (NN+1);                         // N
  int*   elist= fill + NN;                            // E
  float* AttnP= (float*)(elist + EE);                 // E*4

  hipMemsetAsync(Stats, 0, (64 + NN + 16)*sizeof(int), stream);

  k_f0f1      <<<dim3(3, NN/16),        64,  0, stream>>>(frame, Wf0, bf0, Wf1, bf1, f0f1);
  k_node2     <<<dim3(NN/4),            256, 0, stream>>>(f0f1, rot, trans, tfn, Wgs, Wgv, Wqs, Wqv, Gs, Gv, Qs, Qv);
  k_hist      <<<dim3((EE+255)/256),    256, 0, stream>>>(ei, cnt);
  k_scan      <<<dim3(1),               256, 0, stream>>>(cnt, ofs, fill);
  k_scatter   <<<dim3((EE+255)/256),    256, 0, stream>>>(ei, fill, elist);
  k_edge_k_ab <<<dim3(EE/256),          256, 0, stream>>>(ei, esh, ef, Gs, Gv, Qs, Wk1, bk1, Wk2, bk2, AttnP);
  k_edge_k_cde<<<dim3(EE/256),          256, 0, stream>>>(ei, esh, ef, Gs, Gv, Qv, Wk1, bk1, Wk2, bk2, AttnP, Attn);
  k_edge_v_ab <<<dim3(EE/256),          256, 0, stream>>>(ei, esh, ef, Gs, Gv, Wv1, bv1, Wv2, bv2, EdgeV);
  k_edge_v_cde<<<dim3(EE/256),          256, 0, stream>>>(ei, esh, ef, Gs, Gv, Wv1, bv1, Wv2, bv2, EdgeV);
  k_reduce    <<<dim3((NN+3)/4),        256, 0, stream>>>(ofs, elist, Attn, EdgeV, Upd);
  k_nodeout   <<<dim3((NN+255)/256),    256, 0, stream>>>(Upd, tfn, Wos, Wov, Wss, Wsv, Pre, Stats);
  k_final     <<<dim3((NN*40+255)/256), 256, 0, stream>>>(Pre, Stats, bnws, bnbs, bnwv, (float*)d_out);
}

// Round 4
// 551.719 us; speedup vs baseline: 2.1773x; 1.2753x over previous
//
#include <hip/hip_runtime.h>
#include <hip/hip_bf16.h>
#include <math.h>

#define NN 10000
#define EE 160000
#define CSZ 128

#define INV_S8  0.35355339059327373f   // 1/sqrt(8)
#define INV_S32 0.17677669529663687f   // 1/sqrt(32)
#define INV_S2  0.7071067811865476f    // 1/sqrt(2)
#define INV_S3  0.5773502691896258f    // 1/sqrt(3)

typedef short s16x8 __attribute__((ext_vector_type(8)));
typedef float f32x4 __attribute__((ext_vector_type(4)));

__device__ __forceinline__ unsigned short f2bf(float f){
  __hip_bfloat16 h = __float2bfloat16(f);
  return *reinterpret_cast<unsigned short*>(&h);
}

// ---------------- Kernel 1: f0 = frame@Wf0+b, f1raw = frame@Wf1+b ----------
__global__ __launch_bounds__(64) void k_f0f1(
    const float* __restrict__ frame,
    const float* __restrict__ Wf0, const float* __restrict__ bf0,
    const float* __restrict__ Wf1, const float* __restrict__ bf1,
    float* __restrict__ f0f1){
  int c = blockIdx.x*64 + threadIdx.x;
  int n0 = blockIdx.y*16;
  if(c >= 160) return;
  bool is0 = c < 64;
  int cc = is0 ? c : (c-64);
  float acc[16];
  float b = is0 ? bf0[cc] : bf1[cc];
  #pragma unroll
  for(int j=0;j<16;j++) acc[j] = b;
  for(int k=0;k<CSZ;k++){
    float w = is0 ? Wf0[k*64+cc] : Wf1[k*96+cc];
    #pragma unroll
    for(int j=0;j<16;j++)
      acc[j] = fmaf(frame[(size_t)(n0+j)*CSZ + k], w, acc[j]);
  }
  #pragma unroll
  for(int j=0;j<16;j++) f0f1[(size_t)(n0+j)*160 + c] = acc[j];
}

// ---------------- Kernel 2: rotate f1, gs, gv, q_s, q_v --------------------
__global__ __launch_bounds__(256) void k_node2(
    const float* __restrict__ f0f1, const float* __restrict__ rot,
    const float* __restrict__ trans, const float* __restrict__ tfn,
    const float* __restrict__ Wgs, const float* __restrict__ Wgv,
    const float* __restrict__ Wqs, const float* __restrict__ Wqv,
    float* __restrict__ Gs, float* __restrict__ Gv,
    float* __restrict__ Qs, float* __restrict__ Qv){
  __shared__ float f1r[4][32][3];
  int ln = threadIdx.x & 63;
  int g  = threadIdx.x >> 6;
  int n  = blockIdx.x*4 + g;
  if(n < NN && ln < 32){
    int u = ln;
    float v0 = f0f1[(size_t)n*160 + 64 + u*3 + 0];
    float v1 = f0f1[(size_t)n*160 + 64 + u*3 + 1];
    float v2 = f0f1[(size_t)n*160 + 64 + u*3 + 2];
    const float* R = rot + (size_t)n*9;
    const float* t = trans + (size_t)n*3;
    f1r[g][u][0] = R[0]*v0 + R[1]*v1 + R[2]*v2 + t[0];
    f1r[g][u][1] = R[3]*v0 + R[4]*v1 + R[5]*v2 + t[1];
    f1r[g][u][2] = R[6]*v0 + R[7]*v1 + R[8]*v2 + t[2];
  }
  __syncthreads();
  if(n >= NN) return;
  if(ln < 16){
    int w = ln; float a = 0.f;
    for(int u=0;u<64;u++) a = fmaf(f0f1[(size_t)n*160+u], Wgs[u*16+w], a);
    Gs[(size_t)n*16+w] = a * 0.125f;
  } else if(ln < 40){
    int idx = ln-16, w = idx/3, i = idx%3; float a = 0.f;
    for(int u=0;u<32;u++) a = fmaf(f1r[g][u][i], Wgv[u*8+w], a);
    Gv[(size_t)n*24+idx] = a * INV_S32;
  }
  if(ln < 16){
    int w = ln; float a = 0.f;
    for(int u=0;u<16;u++) a = fmaf(tfn[(size_t)n*40+u], Wqs[u*16+w], a);
    Qs[(size_t)n*16+w] = a * 0.25f;
  } else if(ln < 40){
    int idx = ln-16, w = idx/3, i = idx%3; float a = 0.f;
    for(int u=0;u<8;u++) a = fmaf(tfn[(size_t)n*40+16+u*3+i], Wqv[u*8+w], a);
    Qv[(size_t)n*24+idx] = a * INV_S8;
  }
}

// ---------------- CSR build ------------------------------------------------
__global__ __launch_bounds__(256) void k_hist(const int* __restrict__ ei, int* __restrict__ cnt){
  int e = blockIdx.x*256 + threadIdx.x;
  if(e < EE) atomicAdd(&cnt[ei[EE + e]], 1);
}

__global__ __launch_bounds__(256) void k_scan(const int* __restrict__ cnt,
                                              int* __restrict__ ofs, int* __restrict__ fill){
  __shared__ int tsum[256];
  int t = threadIdx.x;
  const int CH = (NN + 255)/256;
  int base = t*CH;
  int s = 0;
  for(int i=0;i<CH;i++){ int idx=base+i; if(idx<NN) s += cnt[idx]; }
  tsum[t] = s;
  __syncthreads();
  for(int off=1; off<256; off<<=1){
    int v = (t>=off)? tsum[t-off] : 0;
    __syncthreads();
    tsum[t] += v;
    __syncthreads();
  }
  int run = (t==0)? 0 : tsum[t-1];
  for(int i=0;i<CH;i++){
    int idx = base+i;
    if(idx < NN){ ofs[idx] = run; fill[idx] = run; run += cnt[idx]; }
  }
  if(t==255) ofs[NN] = tsum[255];
}

__global__ __launch_bounds__(256) void k_scatter(const int* __restrict__ ei,
                                                 int* __restrict__ fill, int* __restrict__ elist){
  int e = blockIdx.x*256 + threadIdx.x;
  if(e >= EE) return;
  int src = ei[EE + e];
  int pos = atomicAdd(&fill[src], 1);
  elist[pos] = e;
}

// ---------------- Weight reshape: W2 -> MFMA B-fragment order, bf16 --------
// B2r element (ntile, g, col, j) = W2[h=g*8+j][c=ntile*16+col] * colscale
// colscale = INV_S2 for c<384, INV_S3 for c>=384 (both branches).
__global__ __launch_bounds__(256) void k_prepw(
    const float* __restrict__ Wk2, const float* __restrict__ bk2,
    const float* __restrict__ Wv2, const float* __restrict__ bv2,
    unsigned short* __restrict__ B2rK, unsigned short* __restrict__ B2rV,
    float* __restrict__ biasK, float* __restrict__ biasV){
  int tid = blockIdx.x*256 + threadIdx.x;
  const int NV = 896*32, NK = 640*32;
  if(tid < NV){
    int c = tid>>5, h = tid&31;
    float s = (c<384)? INV_S2 : INV_S3;
    B2rV[(c>>4)*512 + (h>>3)*128 + (c&15)*8 + (h&7)] = f2bf(Wv2[h*896+c]*s);
  } else if(tid < NV+NK){
    int i = tid - NV; int c = i>>5, h = i&31;
    float s = (c<384)? INV_S2 : INV_S3;
    B2rK[(c>>4)*512 + (h>>3)*128 + (c&15)*8 + (h&7)] = f2bf(Wk2[h*640+c]*s);
  } else if(tid < NV+NK+896){
    int c = tid - (NV+NK);
    biasV[c] = bv2[c] * ((c<384)? INV_S2 : INV_S3);
  } else if(tid < NV+NK+896+640){
    int c = tid - (NV+NK+896);
    biasK[c] = bk2[c] * ((c<384)? INV_S2 : INV_S3);
  }
}

// ---------------- Fused edge kernel: MFMA two-stage, K+V, logits + EdgeV ---
// 1 wave per block, 64 edges per wave, zero barriers.
// stage 1: kw[64 edges][32 cols] = bias + hid @ W2  (bf16 MFMA, A=hid frags)
// stage 2: lane=edge applies TP coefficients from registers.
__global__ __launch_bounds__(64) void k_edge(
    const int* __restrict__ ei, const float* __restrict__ esh,
    const float* __restrict__ ef,
    const float* __restrict__ Gs, const float* __restrict__ Gv,
    const float* __restrict__ Qs, const float* __restrict__ Qv,
    const float* __restrict__ Wk1, const float* __restrict__ bk1,
    const float* __restrict__ Wv1, const float* __restrict__ bv1,
    const unsigned short* __restrict__ B2rK, const float* __restrict__ biasK,
    const unsigned short* __restrict__ B2rV, const float* __restrict__ biasV,
    float* __restrict__ Attn, float* __restrict__ EdgeV){
  __shared__ float kwL[32*68];            // col-major [col][68: 64 edges + pad]
  __shared__ unsigned short hVL[2048];    // hid_v frags: [(t*4+g)*16 + row]*8 + j
  __shared__ unsigned short hKL[2048];

  int lane = threadIdx.x;
  int e = blockIdx.x*64 + lane;
  int dst = ei[e], src = ei[EE + e];
  float4 sh4 = *(const float4*)(esh + (size_t)e*4);
  float shs = sh4.x, sv0 = sh4.y, sv1 = sh4.z, sv2 = sh4.w;
  float shsI8 = shs * INV_S8;

  // --- per-edge features (all in registers, static indexing) ---
  float fsn[16];
  { const float4* g4 = (const float4*)(Gs + (size_t)dst*16);
    #pragma unroll
    for(int q=0;q<4;q++){ float4 t = g4[q];
      fsn[q*4+0]=t.x*0.25f; fsn[q*4+1]=t.y*0.25f; fsn[q*4+2]=t.z*0.25f; fsn[q*4+3]=t.w*0.25f; } }
  float fv[24];
  { const float4* g4 = (const float4*)(Gv + (size_t)dst*24);
    #pragma unroll
    for(int q=0;q<6;q++){ float4 t = g4[q];
      fv[q*4+0]=t.x; fv[q*4+1]=t.y; fv[q*4+2]=t.z; fv[q*4+3]=t.w; } }
  float dv[8], crs[24];
  #pragma unroll
  for(int u=0;u<8;u++){
    float a0=fv[u*3+0], a1=fv[u*3+1], a2=fv[u*3+2];
    dv[u] = (a0*sv0 + a1*sv1 + a2*sv2) * INV_S8;
    crs[u*3+0] = (a1*sv2 - a2*sv1)*INV_S8;
    crs[u*3+1] = (a2*sv0 - a0*sv2)*INV_S8;
    crs[u*3+2] = (a0*sv1 - a1*sv0)*INV_S8;
  }

  // --- both MLPs (hidden = relu(ef@W1+b1)) ---
  {
    float efv[32];
    const float4* efp = (const float4*)(ef + (size_t)e*32);
    #pragma unroll
    for(int q=0;q<8;q++){ float4 t=efp[q]; efv[q*4]=t.x; efv[q*4+1]=t.y; efv[q*4+2]=t.z; efv[q*4+3]=t.w; }
    float hk[32], hv[32];
    #pragma unroll
    for(int h=0;h<32;h++){ hk[h]=bk1[h]; hv[h]=bv1[h]; }
    #pragma unroll
    for(int k=0;k<32;k++){
      float ekv = efv[k];
      #pragma unroll
      for(int h=0;h<32;h++){
        hk[h] = fmaf(ekv, Wk1[k*32+h], hk[h]);
        hv[h] = fmaf(ekv, Wv1[k*32+h], hv[h]);
      }
    }
    // write hid to LDS as bf16 in A-fragment layout
    int t = lane>>4, row = lane&15;
    #pragma unroll
    for(int g=0;g<4;g++){
      s16x8 pv, pk;
      #pragma unroll
      for(int j=0;j<8;j++){
        pv[j] = (short)f2bf(fmaxf(hv[g*8+j], 0.f));
        pk[j] = (short)f2bf(fmaxf(hk[g*8+j], 0.f));
      }
      *(s16x8*)&hVL[((t*4+g)*16 + row)*8] = pv;
      *(s16x8*)&hKL[((t*4+g)*16 + row)*8] = pk;
    }
  }
  // A-fragment reads (same-wave DS pipe is in-order; RAW is safe)
  s16x8 afV[4];
  #pragma unroll
  for(int tt=0;tt<4;tt++)
    afV[tt] = *(const s16x8*)&hVL[((tt*4 + (lane>>4))*16 + (lane&15))*8];

  // =================== V phase: 28 chunks of 32 cols =======================
  float a16[16], cs[16], vv[48];
  #pragma unroll
  for(int w=0;w<16;w++){ a16[w]=0.f; cs[w]=0.f; }
  #pragma unroll
  for(int j=0;j<48;j++) vv[j]=0.f;

  #pragma unroll
  for(int ch=0; ch<28; ++ch){
    // stage 1: kw chunk via MFMA
    #pragma unroll
    for(int nt=0; nt<2; ++nt){
      int ntile = ch*2+nt;
      s16x8 bf = *(const s16x8*)&B2rV[ntile*512 + (lane>>4)*128 + (lane&15)*8];
      float bval = biasV[ntile*16 + (lane&15)];
      #pragma unroll
      for(int tt=0; tt<4; ++tt){
        f32x4 acc = {bval, bval, bval, bval};
        acc = __builtin_amdgcn_mfma_f32_16x16x32_bf16(afV[tt], bf, acc, 0, 0, 0);
        *(f32x4*)&kwL[(nt*16 + (lane&15))*68 + tt*16 + (lane>>4)*4] = acc;
      }
    }
    // stage 2: apply (lane = edge)
    #pragma unroll
    for(int j=0; j<32; ++j){
      float kw = kwL[j*68 + lane];
      if(ch < 8){                 // path A (scalar): cols 0..255
        int u = ch*2 + (j>>4), w = j&15;
        a16[w] = fmaf(fsn[u], kw, a16[w]);
      } else if(ch < 12){         // path B (scalar): cols 256..383
        int u = (ch-8)*2 + (j>>4), w = j&15;
        a16[w] = fmaf(dv[u], kw, a16[w]);
      } else if(ch < 20){         // path C: cols 384..639
        int u = (ch-12)*2 + (j>>4), w = j&15;
        cs[w] = fmaf(fsn[u], kw, cs[w]);
      } else if(ch < 24){         // path D: cols 640..767
        int u = (ch-20)*2 + (j>>4), w = j&15;
        float t2 = kw*shsI8;
        vv[w*3+0] = fmaf(fv[u*3+0], t2, vv[w*3+0]);
        vv[w*3+1] = fmaf(fv[u*3+1], t2, vv[w*3+1]);
        vv[w*3+2] = fmaf(fv[u*3+2], t2, vv[w*3+2]);
      } else {                    // path E: cols 768..895
        int u = (ch-24)*2 + (j>>4), w = j&15;
        vv[w*3+0] = fmaf(crs[u*3+0], kw, vv[w*3+0]);
        vv[w*3+1] = fmaf(crs[u*3+1], kw, vv[w*3+1]);
        vv[w*3+2] = fmaf(crs[u*3+2], kw, vv[w*3+2]);
      }
    }
    if(ch == 7){                  // fold shs into path-A accumulation
      #pragma unroll
      for(int w=0;w<16;w++) a16[w] *= shs;
    }
  }
  // fold C into vv, store EdgeV (scales already in B/bias)
  #pragma unroll
  for(int w=0;w<16;w++){
    vv[w*3+0] = fmaf(cs[w], sv0, vv[w*3+0]);
    vv[w*3+1] = fmaf(cs[w], sv1, vv[w*3+1]);
    vv[w*3+2] = fmaf(cs[w], sv2, vv[w*3+2]);
  }
  {
    float* out = EdgeV + (size_t)e*64;
    #pragma unroll
    for(int q=0;q<4;q++)
      ((float4*)out)[q] = make_float4(a16[q*4], a16[q*4+1], a16[q*4+2], a16[q*4+3]);
    #pragma unroll
    for(int q=0;q<12;q++)
      ((float4*)out)[4+q] = make_float4(vv[q*4], vv[q*4+1], vv[q*4+2], vv[q*4+3]);
  }

  // =================== K phase: 20 chunks of 32 cols =======================
  s16x8 afK[4];
  #pragma unroll
  for(int tt=0;tt<4;tt++)
    afK[tt] = *(const s16x8*)&hKL[((tt*4 + (lane>>4))*16 + (lane&15))*8];

  float ks[16], cs8[8], kv[24];
  #pragma unroll
  for(int w=0;w<16;w++) ks[w]=0.f;
  #pragma unroll
  for(int w=0;w<8;w++) cs8[w]=0.f;
  #pragma unroll
  for(int j=0;j<24;j++) kv[j]=0.f;

  #pragma unroll
  for(int ch=0; ch<20; ++ch){
    #pragma unroll
    for(int nt=0; nt<2; ++nt){
      int ntile = ch*2+nt;
      s16x8 bf = *(const s16x8*)&B2rK[ntile*512 + (lane>>4)*128 + (lane&15)*8];
      float bval = biasK[ntile*16 + (lane&15)];
      #pragma unroll
      for(int tt=0; tt<4; ++tt){
        f32x4 acc = {bval, bval, bval, bval};
        acc = __builtin_amdgcn_mfma_f32_16x16x32_bf16(afK[tt], bf, acc, 0, 0, 0);
        *(f32x4*)&kwL[(nt*16 + (lane&15))*68 + tt*16 + (lane>>4)*4] = acc;
      }
    }
    #pragma unroll
    for(int j=0; j<32; ++j){
      float kw = kwL[j*68 + lane];
      if(ch < 8){                 // path A: cols 0..255
        int u = ch*2 + (j>>4), w = j&15;
        ks[w] = fmaf(fsn[u], kw, ks[w]);
      } else if(ch < 12){         // path B: cols 256..383
        int u = (ch-8)*2 + (j>>4), w = j&15;
        ks[w] = fmaf(dv[u], kw, ks[w]);
      } else if(ch < 16){         // path C: cols 384..511 (w<8)
        int u = (ch-12)*4 + (j>>3), w = j&7;
        cs8[w] = fmaf(fsn[u], kw, cs8[w]);
      } else if(ch < 18){         // path D: cols 512..575
        int u = (ch-16)*4 + (j>>3), w = j&7;
        float t2 = kw*shsI8;
        kv[w*3+0] = fmaf(fv[u*3+0], t2, kv[w*3+0]);
        kv[w*3+1] = fmaf(fv[u*3+1], t2, kv[w*3+1]);
        kv[w*3+2] = fmaf(fv[u*3+2], t2, kv[w*3+2]);
      } else {                    // path E: cols 576..639
        int u = (ch-18)*4 + (j>>3), w = j&7;
        kv[w*3+0] = fmaf(crs[u*3+0], kw, kv[w*3+0]);
        kv[w*3+1] = fmaf(crs[u*3+1], kw, kv[w*3+1]);
        kv[w*3+2] = fmaf(crs[u*3+2], kw, kv[w*3+2]);
      }
    }
    if(ch == 7){
      #pragma unroll
      for(int w=0;w<16;w++) ks[w] *= shs;
    }
  }
  #pragma unroll
  for(int w=0;w<8;w++){
    kv[w*3+0] = fmaf(cs8[w], sv0, kv[w*3+0]);
    kv[w*3+1] = fmaf(cs8[w], sv1, kv[w*3+1]);
    kv[w*3+2] = fmaf(cs8[w], sv2, kv[w*3+2]);
  }
  // logits
  {
    const float* qsp = Qs + (size_t)src*16;
    const float* qvp = Qv + (size_t)src*24;
    float at[4];
    #pragma unroll
    for(int h=0;h<4;h++){
      float a = 0.f;
      #pragma unroll
      for(int j=0;j<4;j++) a = fmaf(qsp[h*4+j], ks[h*4+j], a);
      #pragma unroll
      for(int j=0;j<6;j++) a = fmaf(qvp[h*6+j], kv[h*6+j], a);
      at[h] = a;
    }
    *(float4*)(Attn + (size_t)e*4) = make_float4(at[0], at[1], at[2], at[3]);
  }
}

// ---------------- per-node softmax + weighted sum (no atomics) -------------
__global__ __launch_bounds__(256) void k_reduce(
    const int* __restrict__ ofs, const int* __restrict__ elist,
    const float* __restrict__ Attn, const float* __restrict__ EdgeV,
    float* __restrict__ Upd){
  int wid = threadIdx.x >> 6, ln = threadIdx.x & 63;
  int n = blockIdx.x*4 + wid;
  if(n >= NN) return;
  int beg = ofs[n], end = ofs[n+1];
  float m0=-3.4e38f, m1=-3.4e38f, m2=-3.4e38f, m3=-3.4e38f;
  for(int i=beg+ln; i<end; i+=64){
    int e = elist[i];
    float4 a = *(const float4*)(Attn + (size_t)e*4);
    m0=fmaxf(m0,a.x); m1=fmaxf(m1,a.y); m2=fmaxf(m2,a.z); m3=fmaxf(m3,a.w);
  }
  #pragma unroll
  for(int off=1; off<64; off<<=1){
    m0=fmaxf(m0,__shfl_xor(m0,off)); m1=fmaxf(m1,__shfl_xor(m1,off));
    m2=fmaxf(m2,__shfl_xor(m2,off)); m3=fmaxf(m3,__shfl_xor(m3,off));
  }
  int h = (ln < 16) ? (ln >> 2) : (((ln - 16)/3) >> 2);
  float mh = (h==0)?m0:(h==1)?m1:(h==2)?m2:m3;
  float acc = 0.f, den = 0.f;
  for(int i=beg; i<end; i++){
    int e = elist[i];
    float v  = EdgeV[(size_t)e*64 + ln];
    float a  = Attn[(size_t)e*4 + h];
    float ex = __expf(a - mh);
    acc = fmaf(ex, v, acc);
    den += ex;
  }
  Upd[(size_t)n*64 + ln] = acc / (den + 1e-9f);
}

// ---------------- node output GEMMs + BN stats -----------------------------
__global__ __launch_bounds__(256) void k_nodeout(
    const float* __restrict__ Upd, const float* __restrict__ tfn,
    const float* __restrict__ Wos, const float* __restrict__ Wov,
    const float* __restrict__ Wss, const float* __restrict__ Wsv,
    float* __restrict__ Pre, float* __restrict__ Stats){
  int n = blockIdx.x*256 + threadIdx.x;
  int lane = threadIdx.x & 63;
  float os[16], ov[24];
  if(n < NN){
    float us[16];
    #pragma unroll
    for(int u=0;u<16;u++) us[u] = Upd[(size_t)n*64+u];
    float uv[48];
    #pragma unroll
    for(int j=0;j<48;j++) uv[j] = Upd[(size_t)n*64+16+j];
    float ts[16];
    #pragma unroll
    for(int u=0;u<16;u++) ts[u] = tfn[(size_t)n*40+u];
    #pragma unroll
    for(int w=0;w<16;w++){
      float a=0.f, b=0.f;
      #pragma unroll
      for(int u=0;u<16;u++){ a = fmaf(us[u], Wos[u*16+w], a); b = fmaf(ts[u], Wss[u*16+w], b); }
      os[w] = (a + b)*0.25f;
    }
    float tv[24];
    #pragma unroll
    for(int j=0;j<24;j++) tv[j] = tfn[(size_t)n*40+16+j];
    #pragma unroll
    for(int w=0;w<8;w++){
      #pragma unroll
      for(int i=0;i<3;i++){
        float a=0.f;
        #pragma unroll
        for(int u=0;u<16;u++) a = fmaf(uv[u*3+i], Wov[u*8+w], a);
        float b=0.f;
        #pragma unroll
        for(int u=0;u<8;u++) b = fmaf(tv[u*3+i], Wsv[u*8+w], b);
        ov[w*3+i] = a*0.25f + b*INV_S8;
      }
    }
    float* p = Pre + (size_t)n*40;
    #pragma unroll
    for(int w=0;w<16;w++) p[w] = os[w];
    #pragma unroll
    for(int j=0;j<24;j++) p[16+j] = ov[j];
  } else {
    #pragma unroll
    for(int w=0;w<16;w++) os[w]=0.f;
    #pragma unroll
    for(int j=0;j<24;j++) ov[j]=0.f;
  }
#define WAVE_RED_ADD(v) { v += __shfl_xor(v,1); v += __shfl_xor(v,2); v += __shfl_xor(v,4); \
                          v += __shfl_xor(v,8); v += __shfl_xor(v,16); v += __shfl_xor(v,32); }
  #pragma unroll
  for(int c=0;c<16;c++){
    float s = os[c];       WAVE_RED_ADD(s);
    float q = os[c]*os[c]; WAVE_RED_ADD(q);
    if(lane==0){ atomicAdd(&Stats[c], s); atomicAdd(&Stats[16+c], q); }
  }
  #pragma unroll
  for(int w=0;w<8;w++){
    float q = ov[w*3]*ov[w*3] + ov[w*3+1]*ov[w*3+1] + ov[w*3+2]*ov[w*3+2];
    WAVE_RED_ADD(q);
    if(lane==0) atomicAdd(&Stats[32+w], q);
  }
#undef WAVE_RED_ADD
}

// ---------------- finalize BN + write output -------------------------------
__global__ __launch_bounds__(256) void k_final(
    const float* __restrict__ Pre, const float* __restrict__ Stats,
    const float* __restrict__ bnws, const float* __restrict__ bnbs,
    const float* __restrict__ bnwv, float* __restrict__ Out){
  int idx = blockIdx.x*256 + threadIdx.x;
  if(idx >= NN*40) return;
  int n = idx/40, c = idx - n*40;
  float x = Pre[idx];
  float r;
  if(c < 16){
    float mu  = Stats[c]    * (1.f/NN);
    float var = Stats[16+c] * (1.f/NN) - mu*mu;
    r = (x - mu) / sqrtf(var + 1e-5f) * bnws[c] + bnbs[c];
  } else {
    int w = (c-16)/3;
    float n2 = Stats[32+w] * (1.f/NN);
    r = x / sqrtf(n2 + 1e-5f) * bnwv[w];
  }
  Out[idx] = r;
}

extern "C" void kernel_launch(void* const* d_in, const int* in_sizes, int n_in,
                              void* d_out, int out_size, void* d_ws, size_t ws_size,
                              hipStream_t stream){
  const float* frame = (const float*)d_in[0];
  const float* rot   = (const float*)d_in[1];
  const float* trans = (const float*)d_in[2];
  const float* tfn   = (const float*)d_in[3];
  const float* ef    = (const float*)d_in[4];
  const float* esh   = (const float*)d_in[5];
  const int*   ei    = (const int*)  d_in[6];
  const float* Wf0   = (const float*)d_in[7];
  const float* bf0   = (const float*)d_in[8];
  const float* Wf1   = (const float*)d_in[9];
  const float* bf1   = (const float*)d_in[10];
  const float* Wgs   = (const float*)d_in[11];
  const float* Wgv   = (const float*)d_in[12];
  const float* Wqs   = (const float*)d_in[13];
  const float* Wqv   = (const float*)d_in[14];
  const float* Wk1   = (const float*)d_in[15];
  const float* bk1   = (const float*)d_in[16];
  const float* Wk2   = (const float*)d_in[17];
  const float* bk2   = (const float*)d_in[18];
  const float* Wv1   = (const float*)d_in[19];
  const float* bv1   = (const float*)d_in[20];
  const float* Wv2   = (const float*)d_in[21];
  const float* bv2   = (const float*)d_in[22];
  const float* Wos   = (const float*)d_in[23];
  const float* Wov   = (const float*)d_in[24];
  const float* Wss   = (const float*)d_in[25];
  const float* Wsv   = (const float*)d_in[26];
  const float* bnws  = (const float*)d_in[27];
  const float* bnbs  = (const float*)d_in[28];
  const float* bnwv  = (const float*)d_in[29];

  float* ws   = (float*)d_ws;
  float* f0f1 = ws;                                   // N*160
  float* Gs   = f0f1 + (size_t)NN*160;                // N*16
  float* Gv   = Gs   + (size_t)NN*16;                 // N*24
  float* Qs   = Gv   + (size_t)NN*24;                 // N*16
  float* Qv   = Qs   + (size_t)NN*16;                 // N*24
  float* Attn = Qv   + (size_t)NN*24;                 // E*4
  float* Pre  = Attn + (size_t)EE*4;                  // N*40
  float* Upd  = Pre  + (size_t)NN*40;                 // N*64
  float* EdgeV= Upd  + (size_t)NN*64;                 // E*64
  float* Stats= EdgeV+ (size_t)EE*64;                 // 64 floats (zeroed)
  int*   cnt  = (int*)(Stats + 64);                   // N+16   (zeroed)
  int*   ofs  = cnt + (NN+16);                        // N+1
  int*   fill = ofs + (NN+1);                         // N
  int*   elist= fill + NN;                            // E
  float* biasV= (float*)(elist + EE);                 // 896
  float* biasK= biasV + 896;                          // 640
  unsigned short* B2rV = (unsigned short*)(biasK + 640);  // 896*32
  unsigned short* B2rK = B2rV + 896*32;                   // 640*32

  hipMemsetAsync(Stats, 0, (64 + NN + 16)*sizeof(int), stream);

  k_f0f1   <<<dim3(3, NN/16),        64,  0, stream>>>(frame, Wf0, bf0, Wf1, bf1, f0f1);
  k_prepw  <<<dim3(198),             256, 0, stream>>>(Wk2, bk2, Wv2, bv2, B2rK, B2rV, biasK, biasV);
  k_node2  <<<dim3(NN/4),            256, 0, stream>>>(f0f1, rot, trans, tfn, Wgs, Wgv, Wqs, Wqv, Gs, Gv, Qs, Qv);
  k_hist   <<<dim3((EE+255)/256),    256, 0, stream>>>(ei, cnt);
  k_scan   <<<dim3(1),               256, 0, stream>>>(cnt, ofs, fill);
  k_scatter<<<dim3((EE+255)/256),    256, 0, stream>>>(ei, fill, elist);
  k_edge   <<<dim3(EE/64),           64,  0, stream>>>(ei, esh, ef, Gs, Gv, Qs, Qv,
                                                       Wk1, bk1, Wv1, bv1,
                                                       B2rK, biasK, B2rV, biasV,
                                                       Attn, EdgeV);
  k_reduce <<<dim3((NN+3)/4),        256, 0, stream>>>(ofs, elist, Attn, EdgeV, Upd);
  k_nodeout<<<dim3((NN+255)/256),    256, 0, stream>>>(Upd, tfn, Wos, Wov, Wss, Wsv, Pre, Stats);
  k_final  <<<dim3((NN*40+255)/256), 256, 0, stream>>>(Pre, Stats, bnws, bnbs, bnwv, (float*)d_out);
}

// Round 5
// 385.164 us; speedup vs baseline: 3.1189x; 1.4324x over previous
//
#include <hip/hip_runtime.h>
#include <hip/hip_bf16.h>
#include <math.h>

#define NN 10000
#define EE 160000
#define CSZ 128

#define INV_S8  0.35355339059327373f   // 1/sqrt(8)
#define INV_S32 0.17677669529663687f   // 1/sqrt(32)
#define INV_S2  0.7071067811865476f    // 1/sqrt(2)
#define INV_S3  0.5773502691896258f    // 1/sqrt(3)

typedef short s16x8 __attribute__((ext_vector_type(8)));
typedef float f32x4 __attribute__((ext_vector_type(4)));

__device__ __forceinline__ unsigned short f2bf(float f){
  __hip_bfloat16 h = __float2bfloat16(f);
  return *reinterpret_cast<unsigned short*>(&h);
}

// ---------------- Kernel 1: f0 = frame@Wf0+b, f1raw = frame@Wf1+b ----------
__global__ __launch_bounds__(64) void k_f0f1(
    const float* __restrict__ frame,
    const float* __restrict__ Wf0, const float* __restrict__ bf0,
    const float* __restrict__ Wf1, const float* __restrict__ bf1,
    float* __restrict__ f0f1){
  int c = blockIdx.x*64 + threadIdx.x;
  int n0 = blockIdx.y*16;
  if(c >= 160) return;
  bool is0 = c < 64;
  int cc = is0 ? c : (c-64);
  float acc[16];
  float b = is0 ? bf0[cc] : bf1[cc];
  #pragma unroll
  for(int j=0;j<16;j++) acc[j] = b;
  for(int k=0;k<CSZ;k++){
    float w = is0 ? Wf0[k*64+cc] : Wf1[k*96+cc];
    #pragma unroll
    for(int j=0;j<16;j++)
      acc[j] = fmaf(frame[(size_t)(n0+j)*CSZ + k], w, acc[j]);
  }
  #pragma unroll
  for(int j=0;j<16;j++) f0f1[(size_t)(n0+j)*160 + c] = acc[j];
}

// ---------------- Kernel 2: rotate f1, gs, gv, q_s, q_v --------------------
__global__ __launch_bounds__(256) void k_node2(
    const float* __restrict__ f0f1, const float* __restrict__ rot,
    const float* __restrict__ trans, const float* __restrict__ tfn,
    const float* __restrict__ Wgs, const float* __restrict__ Wgv,
    const float* __restrict__ Wqs, const float* __restrict__ Wqv,
    float* __restrict__ Gs, float* __restrict__ Gv,
    float* __restrict__ Qs, float* __restrict__ Qv){
  __shared__ float f1r[4][32][3];
  int ln = threadIdx.x & 63;
  int g  = threadIdx.x >> 6;
  int n  = blockIdx.x*4 + g;
  if(n < NN && ln < 32){
    int u = ln;
    float v0 = f0f1[(size_t)n*160 + 64 + u*3 + 0];
    float v1 = f0f1[(size_t)n*160 + 64 + u*3 + 1];
    float v2 = f0f1[(size_t)n*160 + 64 + u*3 + 2];
    const float* R = rot + (size_t)n*9;
    const float* t = trans + (size_t)n*3;
    f1r[g][u][0] = R[0]*v0 + R[1]*v1 + R[2]*v2 + t[0];
    f1r[g][u][1] = R[3]*v0 + R[4]*v1 + R[5]*v2 + t[1];
    f1r[g][u][2] = R[6]*v0 + R[7]*v1 + R[8]*v2 + t[2];
  }
  __syncthreads();
  if(n >= NN) return;
  if(ln < 16){
    int w = ln; float a = 0.f;
    for(int u=0;u<64;u++) a = fmaf(f0f1[(size_t)n*160+u], Wgs[u*16+w], a);
    Gs[(size_t)n*16+w] = a * 0.125f;
  } else if(ln < 40){
    int idx = ln-16, w = idx/3, i = idx%3; float a = 0.f;
    for(int u=0;u<32;u++) a = fmaf(f1r[g][u][i], Wgv[u*8+w], a);
    Gv[(size_t)n*24+idx] = a * INV_S32;
  }
  if(ln < 16){
    int w = ln; float a = 0.f;
    for(int u=0;u<16;u++) a = fmaf(tfn[(size_t)n*40+u], Wqs[u*16+w], a);
    Qs[(size_t)n*16+w] = a * 0.25f;
  } else if(ln < 40){
    int idx = ln-16, w = idx/3, i = idx%3; float a = 0.f;
    for(int u=0;u<8;u++) a = fmaf(tfn[(size_t)n*40+16+u*3+i], Wqv[u*8+w], a);
    Qv[(size_t)n*24+idx] = a * INV_S8;
  }
}

// ---------------- CSR build ------------------------------------------------
__global__ __launch_bounds__(256) void k_hist(const int* __restrict__ ei, int* __restrict__ cnt){
  int e = blockIdx.x*256 + threadIdx.x;
  if(e < EE) atomicAdd(&cnt[ei[EE + e]], 1);
}

__global__ __launch_bounds__(256) void k_scan(const int* __restrict__ cnt,
                                              int* __restrict__ ofs, int* __restrict__ fill){
  __shared__ int tsum[256];
  int t = threadIdx.x;
  const int CH = (NN + 255)/256;
  int base = t*CH;
  int s = 0;
  for(int i=0;i<CH;i++){ int idx=base+i; if(idx<NN) s += cnt[idx]; }
  tsum[t] = s;
  __syncthreads();
  for(int off=1; off<256; off<<=1){
    int v = (t>=off)? tsum[t-off] : 0;
    __syncthreads();
    tsum[t] += v;
    __syncthreads();
  }
  int run = (t==0)? 0 : tsum[t-1];
  for(int i=0;i<CH;i++){
    int idx = base+i;
    if(idx < NN){ ofs[idx] = run; fill[idx] = run; run += cnt[idx]; }
  }
  if(t==255) ofs[NN] = tsum[255];
}

__global__ __launch_bounds__(256) void k_scatter(const int* __restrict__ ei,
                                                 int* __restrict__ fill, int* __restrict__ elist){
  int e = blockIdx.x*256 + threadIdx.x;
  if(e >= EE) return;
  int src = ei[EE + e];
  int pos = atomicAdd(&fill[src], 1);
  elist[pos] = e;
}

// ---------------- Weight reshape: W2 -> MFMA B-fragment order, bf16 --------
__global__ __launch_bounds__(256) void k_prepw(
    const float* __restrict__ Wk2, const float* __restrict__ bk2,
    const float* __restrict__ Wv2, const float* __restrict__ bv2,
    unsigned short* __restrict__ B2rK, unsigned short* __restrict__ B2rV,
    float* __restrict__ biasK, float* __restrict__ biasV){
  int tid = blockIdx.x*256 + threadIdx.x;
  const int NV = 896*32, NK = 640*32;
  if(tid < NV){
    int c = tid>>5, h = tid&31;
    float s = (c<384)? INV_S2 : INV_S3;
    B2rV[(c>>4)*512 + (h>>3)*128 + (c&15)*8 + (h&7)] = f2bf(Wv2[h*896+c]*s);
  } else if(tid < NV+NK){
    int i = tid - NV; int c = i>>5, h = i&31;
    float s = (c<384)? INV_S2 : INV_S3;
    B2rK[(c>>4)*512 + (h>>3)*128 + (c&15)*8 + (h&7)] = f2bf(Wk2[h*640+c]*s);
  } else if(tid < NV+NK+896){
    int c = tid - (NV+NK);
    biasV[c] = bv2[c] * ((c<384)? INV_S2 : INV_S3);
  } else if(tid < NV+NK+896+640){
    int c = tid - (NV+NK+896);
    biasK[c] = bk2[c] * ((c<384)? INV_S2 : INV_S3);
  }
}

// MFMA chunk: fill kwL[32 cols][64 edges] for global chunk CH from B2r/bias
#define MFMA_CHUNK(B2r, bias, CH) { \
  _Pragma("unroll") \
  for(int nt=0; nt<2; ++nt){ \
    int ntile = (CH)*2+nt; \
    s16x8 bf = *(const s16x8*)&B2r[ntile*512 + (lane>>4)*128 + (lane&15)*8]; \
    float bval = bias[ntile*16 + (lane&15)]; \
    _Pragma("unroll") \
    for(int tt=0; tt<4; ++tt){ \
      f32x4 acc = {bval, bval, bval, bval}; \
      acc = __builtin_amdgcn_mfma_f32_16x16x32_bf16(af[tt], bf, acc, 0, 0, 0); \
      *(f32x4*)&kwL[(nt*16 + (lane&15))*68 + tt*16 + (lane>>4)*4] = acc; \
    } \
  } }

// hidden MLP -> LDS A-fragments -> af[4] registers
#define HID_TO_FRAGS(W1, b1) { \
  float efv[32]; \
  const float4* efp = (const float4*)(ef + (size_t)e*32); \
  _Pragma("unroll") \
  for(int q=0;q<8;q++){ float4 t=efp[q]; efv[q*4]=t.x; efv[q*4+1]=t.y; efv[q*4+2]=t.z; efv[q*4+3]=t.w; } \
  float hd[32]; \
  _Pragma("unroll") \
  for(int h=0;h<32;h++) hd[h] = b1[h]; \
  _Pragma("unroll") \
  for(int k=0;k<32;k++){ \
    float ekv = efv[k]; \
    _Pragma("unroll") \
    for(int h=0;h<32;h++) hd[h] = fmaf(ekv, W1[k*32+h], hd[h]); \
  } \
  int t = lane>>4, row = lane&15; \
  _Pragma("unroll") \
  for(int g=0;g<4;g++){ \
    s16x8 p; \
    _Pragma("unroll") \
    for(int j=0;j<8;j++) p[j] = (short)f2bf(fmaxf(hd[g*8+j], 0.f)); \
    *(s16x8*)&hL[((t*4+g)*16 + row)*8] = p; \
  } \
  _Pragma("unroll") \
  for(int tt=0;tt<4;tt++) \
    af[tt] = *(const s16x8*)&hL[((tt*4 + (lane>>4))*16 + (lane&15))*8]; }

// ---------------- Edge V kernel: MFMA two-stage, writes EdgeV --------------
__global__ __launch_bounds__(64) void k_edge_v2(
    const int* __restrict__ ei, const float* __restrict__ esh,
    const float* __restrict__ ef,
    const float* __restrict__ Gs, const float* __restrict__ Gv,
    const float* __restrict__ Wv1, const float* __restrict__ bv1,
    const unsigned short* __restrict__ B2rV, const float* __restrict__ biasV,
    float* __restrict__ EdgeV){
  __shared__ float kwL[32*68];
  __shared__ unsigned short hL[2048];
  int lane = threadIdx.x;
  int e = blockIdx.x*64 + lane;
  int dst = ei[e];
  float4 sh4 = *(const float4*)(esh + (size_t)e*4);
  float shs = sh4.x, sv0 = sh4.y, sv1 = sh4.z, sv2 = sh4.w;
  float shsI8 = shs * INV_S8;

  s16x8 af[4];
  HID_TO_FRAGS(Wv1, bv1);

  float fsn[16];
  { const float4* g4 = (const float4*)(Gs + (size_t)dst*16);
    #pragma unroll
    for(int q=0;q<4;q++){ float4 t = g4[q];
      fsn[q*4+0]=t.x*0.25f; fsn[q*4+1]=t.y*0.25f; fsn[q*4+2]=t.z*0.25f; fsn[q*4+3]=t.w*0.25f; } }
  float fv[24];
  { const float4* g4 = (const float4*)(Gv + (size_t)dst*24);
    #pragma unroll
    for(int q=0;q<6;q++){ float4 t = g4[q];
      fv[q*4+0]=t.x; fv[q*4+1]=t.y; fv[q*4+2]=t.z; fv[q*4+3]=t.w; } }

  float* out = EdgeV + (size_t)e*64;

  // ---- path A: chunks 0..7 (cols 0..255) ----
  float a16[16];
  #pragma unroll
  for(int w=0;w<16;w++) a16[w]=0.f;
  #pragma unroll
  for(int ch=0; ch<8; ++ch){
    MFMA_CHUNK(B2rV, biasV, ch);
    #pragma unroll
    for(int j=0;j<32;j++){
      float kw = kwL[j*68 + lane];
      a16[j&15] = fmaf(fsn[ch*2+(j>>4)], kw, a16[j&15]);
    }
  }
  #pragma unroll
  for(int w=0;w<16;w++) a16[w] *= shs;
  // ---- path B: chunks 8..11 (cols 256..383); dv defined here ----
  {
    float dv[8];
    #pragma unroll
    for(int u=0;u<8;u++)
      dv[u] = (fv[u*3+0]*sv0 + fv[u*3+1]*sv1 + fv[u*3+2]*sv2) * INV_S8;
    #pragma unroll
    for(int ch=8; ch<12; ++ch){
      MFMA_CHUNK(B2rV, biasV, ch);
      #pragma unroll
      for(int j=0;j<32;j++){
        float kw = kwL[j*68 + lane];
        a16[j&15] = fmaf(dv[(ch-8)*2+(j>>4)], kw, a16[j&15]);
      }
    }
  }
  // write scalar part now -> a16 dies
  #pragma unroll
  for(int q=0;q<4;q++)
    ((float4*)out)[q] = make_float4(a16[q*4], a16[q*4+1], a16[q*4+2], a16[q*4+3]);

  // ---- path C: chunks 12..19 (cols 384..639) ----
  float cs[16];
  #pragma unroll
  for(int w=0;w<16;w++) cs[w]=0.f;
  #pragma unroll
  for(int ch=12; ch<20; ++ch){
    MFMA_CHUNK(B2rV, biasV, ch);
    #pragma unroll
    for(int j=0;j<32;j++){
      float kw = kwL[j*68 + lane];
      cs[j&15] = fmaf(fsn[(ch-12)*2+(j>>4)], kw, cs[j&15]);
    }
  }
  // ---- path D: chunks 20..23 (cols 640..767) ----
  float vv[48];
  #pragma unroll
  for(int j=0;j<48;j++) vv[j]=0.f;
  #pragma unroll
  for(int ch=20; ch<24; ++ch){
    MFMA_CHUNK(B2rV, biasV, ch);
    #pragma unroll
    for(int j=0;j<32;j++){
      float t2 = kwL[j*68 + lane] * shsI8;
      int u = (ch-20)*2+(j>>4), w = j&15;
      vv[w*3+0] = fmaf(fv[u*3+0], t2, vv[w*3+0]);
      vv[w*3+1] = fmaf(fv[u*3+1], t2, vv[w*3+1]);
      vv[w*3+2] = fmaf(fv[u*3+2], t2, vv[w*3+2]);
    }
  }
  // ---- path E: chunks 24..27 (cols 768..895); crs defined here ----
  {
    float crs[24];
    #pragma unroll
    for(int u=0;u<8;u++){
      float a0=fv[u*3+0], a1=fv[u*3+1], a2=fv[u*3+2];
      crs[u*3+0] = (a1*sv2 - a2*sv1)*INV_S8;
      crs[u*3+1] = (a2*sv0 - a0*sv2)*INV_S8;
      crs[u*3+2] = (a0*sv1 - a1*sv0)*INV_S8;
    }
    #pragma unroll
    for(int ch=24; ch<28; ++ch){
      MFMA_CHUNK(B2rV, biasV, ch);
      #pragma unroll
      for(int j=0;j<32;j++){
        float kw = kwL[j*68 + lane];
        int u = (ch-24)*2+(j>>4), w = j&15;
        vv[w*3+0] = fmaf(crs[u*3+0], kw, vv[w*3+0]);
        vv[w*3+1] = fmaf(crs[u*3+1], kw, vv[w*3+1]);
        vv[w*3+2] = fmaf(crs[u*3+2], kw, vv[w*3+2]);
      }
    }
  }
  // fold C into vv, write vector part
  #pragma unroll
  for(int w=0;w<16;w++){
    vv[w*3+0] = fmaf(cs[w], sv0, vv[w*3+0]);
    vv[w*3+1] = fmaf(cs[w], sv1, vv[w*3+1]);
    vv[w*3+2] = fmaf(cs[w], sv2, vv[w*3+2]);
  }
  #pragma unroll
  for(int q=0;q<12;q++)
    ((float4*)out)[4+q] = make_float4(vv[q*4], vv[q*4+1], vv[q*4+2], vv[q*4+3]);
}

// ---------------- Edge K kernel: MFMA two-stage, writes Attn ---------------
__global__ __launch_bounds__(64) void k_edge_k2(
    const int* __restrict__ ei, const float* __restrict__ esh,
    const float* __restrict__ ef,
    const float* __restrict__ Gs, const float* __restrict__ Gv,
    const float* __restrict__ Qs, const float* __restrict__ Qv,
    const float* __restrict__ Wk1, const float* __restrict__ bk1,
    const unsigned short* __restrict__ B2rK, const float* __restrict__ biasK,
    float* __restrict__ Attn){
  __shared__ float kwL[32*68];
  __shared__ unsigned short hL[2048];
  int lane = threadIdx.x;
  int e = blockIdx.x*64 + lane;
  int dst = ei[e], src = ei[EE + e];
  float4 sh4 = *(const float4*)(esh + (size_t)e*4);
  float shs = sh4.x, sv0 = sh4.y, sv1 = sh4.z, sv2 = sh4.w;
  float shsI8 = shs * INV_S8;

  s16x8 af[4];
  HID_TO_FRAGS(Wk1, bk1);

  float fsn[16];
  { const float4* g4 = (const float4*)(Gs + (size_t)dst*16);
    #pragma unroll
    for(int q=0;q<4;q++){ float4 t = g4[q];
      fsn[q*4+0]=t.x*0.25f; fsn[q*4+1]=t.y*0.25f; fsn[q*4+2]=t.z*0.25f; fsn[q*4+3]=t.w*0.25f; } }
  float fv[24];
  { const float4* g4 = (const float4*)(Gv + (size_t)dst*24);
    #pragma unroll
    for(int q=0;q<6;q++){ float4 t = g4[q];
      fv[q*4+0]=t.x; fv[q*4+1]=t.y; fv[q*4+2]=t.z; fv[q*4+3]=t.w; } }

  // ---- path A: chunks 0..7 ----
  float ks[16];
  #pragma unroll
  for(int w=0;w<16;w++) ks[w]=0.f;
  #pragma unroll
  for(int ch=0; ch<8; ++ch){
    MFMA_CHUNK(B2rK, biasK, ch);
    #pragma unroll
    for(int j=0;j<32;j++){
      float kw = kwL[j*68 + lane];
      ks[j&15] = fmaf(fsn[ch*2+(j>>4)], kw, ks[j&15]);
    }
  }
  #pragma unroll
  for(int w=0;w<16;w++) ks[w] *= shs;
  // ---- path B: chunks 8..11 ----
  {
    float dv[8];
    #pragma unroll
    for(int u=0;u<8;u++)
      dv[u] = (fv[u*3+0]*sv0 + fv[u*3+1]*sv1 + fv[u*3+2]*sv2) * INV_S8;
    #pragma unroll
    for(int ch=8; ch<12; ++ch){
      MFMA_CHUNK(B2rK, biasK, ch);
      #pragma unroll
      for(int j=0;j<32;j++){
        float kw = kwL[j*68 + lane];
        ks[j&15] = fmaf(dv[(ch-8)*2+(j>>4)], kw, ks[j&15]);
      }
    }
  }
  // ---- path C: chunks 12..15 (cols 384..511, w<8) ----
  float cs8[8];
  #pragma unroll
  for(int w=0;w<8;w++) cs8[w]=0.f;
  #pragma unroll
  for(int ch=12; ch<16; ++ch){
    MFMA_CHUNK(B2rK, biasK, ch);
    #pragma unroll
    for(int j=0;j<32;j++){
      float kw = kwL[j*68 + lane];
      cs8[j&7] = fmaf(fsn[(ch-12)*4+(j>>3)], kw, cs8[j&7]);
    }
  }
  // ---- path D: chunks 16..17 ----
  float kv[24];
  #pragma unroll
  for(int j=0;j<24;j++) kv[j]=0.f;
  #pragma unroll
  for(int ch=16; ch<18; ++ch){
    MFMA_CHUNK(B2rK, biasK, ch);
    #pragma unroll
    for(int j=0;j<32;j++){
      float t2 = kwL[j*68 + lane] * shsI8;
      int u = (ch-16)*4+(j>>3), w = j&7;
      kv[w*3+0] = fmaf(fv[u*3+0], t2, kv[w*3+0]);
      kv[w*3+1] = fmaf(fv[u*3+1], t2, kv[w*3+1]);
      kv[w*3+2] = fmaf(fv[u*3+2], t2, kv[w*3+2]);
    }
  }
  // ---- path E: chunks 18..19 ----
  {
    float crs[24];
    #pragma unroll
    for(int u=0;u<8;u++){
      float a0=fv[u*3+0], a1=fv[u*3+1], a2=fv[u*3+2];
      crs[u*3+0] = (a1*sv2 - a2*sv1)*INV_S8;
      crs[u*3+1] = (a2*sv0 - a0*sv2)*INV_S8;
      crs[u*3+2] = (a0*sv1 - a1*sv0)*INV_S8;
    }
    #pragma unroll
    for(int ch=18; ch<20; ++ch){
      MFMA_CHUNK(B2rK, biasK, ch);
      #pragma unroll
      for(int j=0;j<32;j++){
        float kw = kwL[j*68 + lane];
        int u = (ch-18)*4+(j>>3), w = j&7;
        kv[w*3+0] = fmaf(crs[u*3+0], kw, kv[w*3+0]);
        kv[w*3+1] = fmaf(crs[u*3+1], kw, kv[w*3+1]);
        kv[w*3+2] = fmaf(crs[u*3+2], kw, kv[w*3+2]);
      }
    }
  }
  #pragma unroll
  for(int w=0;w<8;w++){
    kv[w*3+0] = fmaf(cs8[w], sv0, kv[w*3+0]);
    kv[w*3+1] = fmaf(cs8[w], sv1, kv[w*3+1]);
    kv[w*3+2] = fmaf(cs8[w], sv2, kv[w*3+2]);
  }
  {
    const float* qsp = Qs + (size_t)src*16;
    const float* qvp = Qv + (size_t)src*24;
    float at[4];
    #pragma unroll
    for(int h=0;h<4;h++){
      float a = 0.f;
      #pragma unroll
      for(int j=0;j<4;j++) a = fmaf(qsp[h*4+j], ks[h*4+j], a);
      #pragma unroll
      for(int j=0;j<6;j++) a = fmaf(qvp[h*6+j], kv[h*6+j], a);
      at[h] = a;
    }
    *(float4*)(Attn + (size_t)e*4) = make_float4(at[0], at[1], at[2], at[3]);
  }
}

// ---------------- per-node softmax + weighted sum (no atomics) -------------
__global__ __launch_bounds__(256) void k_reduce(
    const int* __restrict__ ofs, const int* __restrict__ elist,
    const float* __restrict__ Attn, const float* __restrict__ EdgeV,
    float* __restrict__ Upd){
  int wid = threadIdx.x >> 6, ln = threadIdx.x & 63;
  int n = blockIdx.x*4 + wid;
  if(n >= NN) return;
  int beg = ofs[n], end = ofs[n+1];
  float m0=-3.4e38f, m1=-3.4e38f, m2=-3.4e38f, m3=-3.4e38f;
  for(int i=beg+ln; i<end; i+=64){
    int e = elist[i];
    float4 a = *(const float4*)(Attn + (size_t)e*4);
    m0=fmaxf(m0,a.x); m1=fmaxf(m1,a.y); m2=fmaxf(m2,a.z); m3=fmaxf(m3,a.w);
  }
  #pragma unroll
  for(int off=1; off<64; off<<=1){
    m0=fmaxf(m0,__shfl_xor(m0,off)); m1=fmaxf(m1,__shfl_xor(m1,off));
    m2=fmaxf(m2,__shfl_xor(m2,off)); m3=fmaxf(m3,__shfl_xor(m3,off));
  }
  int h = (ln < 16) ? (ln >> 2) : (((ln - 16)/3) >> 2);
  float mh = (h==0)?m0:(h==1)?m1:(h==2)?m2:m3;
  float acc = 0.f, den = 0.f;
  for(int i=beg; i<end; i++){
    int e = elist[i];
    float v  = EdgeV[(size_t)e*64 + ln];
    float a  = Attn[(size_t)e*4 + h];
    float ex = __expf(a - mh);
    acc = fmaf(ex, v, acc);
    den += ex;
  }
  Upd[(size_t)n*64 + ln] = acc / (den + 1e-9f);
}

// ---------------- node output GEMMs + BN stats -----------------------------
__global__ __launch_bounds__(256) void k_nodeout(
    const float* __restrict__ Upd, const float* __restrict__ tfn,
    const float* __restrict__ Wos, const float* __restrict__ Wov,
    const float* __restrict__ Wss, const float* __restrict__ Wsv,
    float* __restrict__ Pre, float* __restrict__ Stats){
  int n = blockIdx.x*256 + threadIdx.x;
  int lane = threadIdx.x & 63;
  float os[16], ov[24];
  if(n < NN){
    float us[16];
    #pragma unroll
    for(int u=0;u<16;u++) us[u] = Upd[(size_t)n*64+u];
    float uv[48];
    #pragma unroll
    for(int j=0;j<48;j++) uv[j] = Upd[(size_t)n*64+16+j];
    float ts[16];
    #pragma unroll
    for(int u=0;u<16;u++) ts[u] = tfn[(size_t)n*40+u];
    #pragma unroll
    for(int w=0;w<16;w++){
      float a=0.f, b=0.f;
      #pragma unroll
      for(int u=0;u<16;u++){ a = fmaf(us[u], Wos[u*16+w], a); b = fmaf(ts[u], Wss[u*16+w], b); }
      os[w] = (a + b)*0.25f;
    }
    float tv[24];
    #pragma unroll
    for(int j=0;j<24;j++) tv[j] = tfn[(size_t)n*40+16+j];
    #pragma unroll
    for(int w=0;w<8;w++){
      #pragma unroll
      for(int i=0;i<3;i++){
        float a=0.f;
        #pragma unroll
        for(int u=0;u<16;u++) a = fmaf(uv[u*3+i], Wov[u*8+w], a);
        float b=0.f;
        #pragma unroll
        for(int u=0;u<8;u++) b = fmaf(tv[u*3+i], Wsv[u*8+w], b);
        ov[w*3+i] = a*0.25f + b*INV_S8;
      }
    }
    float* p = Pre + (size_t)n*40;
    #pragma unroll
    for(int w=0;w<16;w++) p[w] = os[w];
    #pragma unroll
    for(int j=0;j<24;j++) p[16+j] = ov[j];
  } else {
    #pragma unroll
    for(int w=0;w<16;w++) os[w]=0.f;
    #pragma unroll
    for(int j=0;j<24;j++) ov[j]=0.f;
  }
#define WAVE_RED_ADD(v) { v += __shfl_xor(v,1); v += __shfl_xor(v,2); v += __shfl_xor(v,4); \
                          v += __shfl_xor(v,8); v += __shfl_xor(v,16); v += __shfl_xor(v,32); }
  #pragma unroll
  for(int c=0;c<16;c++){
    float s = os[c];       WAVE_RED_ADD(s);
    float q = os[c]*os[c]; WAVE_RED_ADD(q);
    if(lane==0){ atomicAdd(&Stats[c], s); atomicAdd(&Stats[16+c], q); }
  }
  #pragma unroll
  for(int w=0;w<8;w++){
    float q = ov[w*3]*ov[w*3] + ov[w*3+1]*ov[w*3+1] + ov[w*3+2]*ov[w*3+2];
    WAVE_RED_ADD(q);
    if(lane==0) atomicAdd(&Stats[32+w], q);
  }
#undef WAVE_RED_ADD
}

// ---------------- finalize BN + write output -------------------------------
__global__ __launch_bounds__(256) void k_final(
    const float* __restrict__ Pre, const float* __restrict__ Stats,
    const float* __restrict__ bnws, const float* __restrict__ bnbs,
    const float* __restrict__ bnwv, float* __restrict__ Out){
  int idx = blockIdx.x*256 + threadIdx.x;
  if(idx >= NN*40) return;
  int n = idx/40, c = idx - n*40;
  float x = Pre[idx];
  float r;
  if(c < 16){
    float mu  = Stats[c]    * (1.f/NN);
    float var = Stats[16+c] * (1.f/NN) - mu*mu;
    r = (x - mu) / sqrtf(var + 1e-5f) * bnws[c] + bnbs[c];
  } else {
    int w = (c-16)/3;
    float n2 = Stats[32+w] * (1.f/NN);
    r = x / sqrtf(n2 + 1e-5f) * bnwv[w];
  }
  Out[idx] = r;
}

extern "C" void kernel_launch(void* const* d_in, const int* in_sizes, int n_in,
                              void* d_out, int out_size, void* d_ws, size_t ws_size,
                              hipStream_t stream){
  const float* frame = (const float*)d_in[0];
  const float* rot   = (const float*)d_in[1];
  const float* trans = (const float*)d_in[2];
  const float* tfn   = (const float*)d_in[3];
  const float* ef    = (const float*)d_in[4];
  const float* esh   = (const float*)d_in[5];
  const int*   ei    = (const int*)  d_in[6];
  const float* Wf0   = (const float*)d_in[7];
  const float* bf0   = (const float*)d_in[8];
  const float* Wf1   = (const float*)d_in[9];
  const float* bf1   = (const float*)d_in[10];
  const float* Wgs   = (const float*)d_in[11];
  const float* Wgv   = (const float*)d_in[12];
  const float* Wqs   = (const float*)d_in[13];
  const float* Wqv   = (const float*)d_in[14];
  const float* Wk1   = (const float*)d_in[15];
  const float* bk1   = (const float*)d_in[16];
  const float* Wk2   = (const float*)d_in[17];
  const float* bk2   = (const float*)d_in[18];
  const float* Wv1   = (const float*)d_in[19];
  const float* bv1   = (const float*)d_in[20];
  const float* Wv2   = (const float*)d_in[21];
  const float* bv2   = (const float*)d_in[22];
  const float* Wos   = (const float*)d_in[23];
  const float* Wov   = (const float*)d_in[24];
  const float* Wss   = (const float*)d_in[25];
  const float* Wsv   = (const float*)d_in[26];
  const float* bnws  = (const float*)d_in[27];
  const float* bnbs  = (const float*)d_in[28];
  const float* bnwv  = (const float*)d_in[29];

  float* ws   = (float*)d_ws;
  float* f0f1 = ws;                                   // N*160
  float* Gs   = f0f1 + (size_t)NN*160;                // N*16
  float* Gv   = Gs   + (size_t)NN*16;                 // N*24
  float* Qs   = Gv   + (size_t)NN*24;                 // N*16
  float* Qv   = Qs   + (size_t)NN*16;                 // N*24
  float* Attn = Qv   + (size_t)NN*24;                 // E*4
  float* Pre  = Attn + (size_t)EE*4;                  // N*40
  float* Upd  = Pre  + (size_t)NN*40;                 // N*64
  float* EdgeV= Upd  + (size_t)NN*64;                 // E*64
  float* Stats= EdgeV+ (size_t)EE*64;                 // 64 floats (zeroed)
  int*   cnt  = (int*)(Stats + 64);                   // N+16   (zeroed)
  int*   ofs  = cnt + (NN+16);                        // N+1
  int*   fill = ofs + (NN+1);                         // N
  int*   elist= fill + NN;                            // E
  float* biasV= (float*)(elist + EE);                 // 896
  float* biasK= biasV + 896;                          // 640
  unsigned short* B2rV = (unsigned short*)(biasK + 640);  // 896*32
  unsigned short* B2rK = B2rV + 896*32;                   // 640*32

  hipMemsetAsync(Stats, 0, (64 + NN + 16)*sizeof(int), stream);

  k_f0f1    <<<dim3(3, NN/16),        64,  0, stream>>>(frame, Wf0, bf0, Wf1, bf1, f0f1);
  k_prepw   <<<dim3(198),             256, 0, stream>>>(Wk2, bk2, Wv2, bv2, B2rK, B2rV, biasK, biasV);
  k_node2   <<<dim3(NN/4),            256, 0, stream>>>(f0f1, rot, trans, tfn, Wgs, Wgv, Wqs, Wqv, Gs, Gv, Qs, Qv);
  k_hist    <<<dim3((EE+255)/256),    256, 0, stream>>>(ei, cnt);
  k_scan    <<<dim3(1),               256, 0, stream>>>(cnt, ofs, fill);
  k_scatter <<<dim3((EE+255)/256),    256, 0, stream>>>(ei, fill, elist);
  k_edge_v2 <<<dim3(EE/64),           64,  0, stream>>>(ei, esh, ef, Gs, Gv, Wv1, bv1, B2rV, biasV, EdgeV);
  k_edge_k2 <<<dim3(EE/64),           64,  0, stream>>>(ei, esh, ef, Gs, Gv, Qs, Qv, Wk1, bk1, B2rK, biasK, Attn);
  k_reduce  <<<dim3((NN+3)/4),        256, 0, stream>>>(ofs, elist, Attn, EdgeV, Upd);
  k_nodeout <<<dim3((NN+255)/256),    256, 0, stream>>>(Upd, tfn, Wos, Wov, Wss, Wsv, Pre, Stats);
  k_final   <<<dim3((NN*40+255)/256), 256, 0, stream>>>(Pre, Stats, bnws, bnbs, bnwv, (float*)d_out);
}